// Round 1
// baseline (454.149 us; speedup 1.0000x reference)
//
#include <hip/hip_runtime.h>
#include <math.h>

#define T_TOKENS    16384
#define D_MODEL     2048
#define NUM_EXPERTS 256
#define TOP_K       8
#define MARGIN      6e-5f

// d_out layout (floats): idx | weights | affinities | loss
#define OUT_IDX  0
#define OUT_W    (T_TOKENS * TOP_K)
#define OUT_AFF  (2 * T_TOKENS * TOP_K)
#define OUT_LOSS (2 * T_TOKENS * TOP_K + T_TOKENS * NUM_EXPERTS)

// ws layout (bytes)
#define WS_M64_B   ((size_t)0)                                    // double[256*2048] 4MB
#define WS_MH_B    (WS_M64_B + (size_t)NUM_EXPERTS * D_MODEL * 8) // bf16 1MB
#define WS_ML_B    (WS_MH_B  + (size_t)NUM_EXPERTS * D_MODEL * 2) // bf16 1MB
#define WS_SUMP_B  (WS_ML_B  + (size_t)NUM_EXPERTS * D_MODEL * 2) // double[256]
#define WS_CNT_B   (WS_SUMP_B + NUM_EXPERTS * 8)                  // int[256]
#define WS_NMARG_B (WS_CNT_B  + NUM_EXPERTS * 4)                  // int (+pad)
#define WS_LIST_B  (WS_NMARG_B + 16)                              // int[16384]
#define WS_NCAND_B (WS_LIST_B + (size_t)T_TOKENS * 4)             // int[16384]
#define WS_CAND_B  (WS_NCAND_B + (size_t)T_TOKENS * 4)            // int[16384*64] 4MB
#define WS_CSP_B   (WS_CAND_B + (size_t)T_TOKENS * 64 * 4)        // float[2*512*128] 512KB
#define WS_MP_B    (WS_CSP_B + (size_t)2 * 512 * 128 * 4)         // double[4][256*2048] 16MB

typedef __attribute__((ext_vector_type(8))) short short8;
typedef __attribute__((ext_vector_type(4))) float f32x4;

__device__ __forceinline__ unsigned short bf16_rne(float x) {
    unsigned u = __float_as_uint(x);
    u += 0x7FFFu + ((u >> 16) & 1u);
    return (unsigned short)(u >> 16);
}
__device__ __forceinline__ float bf16_f32(unsigned short h) {
    return __uint_as_float(((unsigned)h) << 16);
}
__device__ __forceinline__ unsigned ford(float f) {
    unsigned u = __float_as_uint(f);
    return ((int)u >= 0) ? (u | 0x80000000u) : ~u;
}
__device__ __forceinline__ float finv(unsigned o) {
    return (o & 0x80000000u) ? __uint_as_float(o ^ 0x80000000u)
                             : __uint_as_float(~o);
}
// async global->LDS, 16B per lane; LDS dest = wave-uniform base + lane*16
__device__ __forceinline__ void glds16(const void* g, void* l) {
    __builtin_amdgcn_global_load_lds(
        (const __attribute__((address_space(1))) unsigned int*)g,
        (__attribute__((address_space(3))) unsigned int*)l,
        16, 0, 0);
}

// ---------------------------------------------------------------------------
// Kernel A1: partial M = C @ W over a D-quarter. tile 32e x 64k, grid (32,8,4)
// = 1024 blocks (4 blocks/CU -> 16 waves/CU for latency hiding).
// ---------------------------------------------------------------------------
__global__ __launch_bounds__(256, 4) void cw_gemm_part(
    const float* __restrict__ C, const float* __restrict__ W,
    double* __restrict__ Mpart)
{
    __shared__ float Cs[32][34];
    __shared__ float Ws[32][68];

    const int tid = threadIdx.x;
    const int tx = tid & 15;
    const int ty = tid >> 4;
    const int e0 = blockIdx.y * 32;
    const int k0 = blockIdx.x * 64;
    const int z  = blockIdx.z;

    double* Mp = Mpart + (size_t)z * NUM_EXPERTS * D_MODEL;
    double acc[2][4] = {{0,0,0,0},{0,0,0,0}};

    for (int d0 = z * 512; d0 < (z + 1) * 512; d0 += 32) {
        {
            const int e = tid >> 3, d4 = (tid & 7) * 4;
            const float4 v = *(const float4*)(C + (size_t)(e0 + e) * D_MODEL + d0 + d4);
            Cs[d4 + 0][e] = v.x; Cs[d4 + 1][e] = v.y;
            Cs[d4 + 2][e] = v.z; Cs[d4 + 3][e] = v.w;
        }
        #pragma unroll
        for (int r = 0; r < 2; ++r) {
            const int idx = tid + r * 256;
            const int d = idx >> 4, k4 = (idx & 15) * 4;
            *(float4*)&Ws[d][k4] =
                *(const float4*)(W + (size_t)(d0 + d) * D_MODEL + k0 + k4);
        }
        __syncthreads();
        #pragma unroll
        for (int dd = 0; dd < 32; ++dd) {
            const float2 a2 = *(const float2*)&Cs[dd][ty * 2];
            const double a0 = (double)a2.x, a1 = (double)a2.y;
            const float4 b4 = *(const float4*)&Ws[dd][tx * 4];
            const double b[4] = {(double)b4.x, (double)b4.y, (double)b4.z, (double)b4.w};
            #pragma unroll
            for (int j = 0; j < 4; ++j) { acc[0][j] += a0 * b[j]; acc[1][j] += a1 * b[j]; }
        }
        __syncthreads();
    }
    #pragma unroll
    for (int i = 0; i < 2; ++i) {
        const int e = e0 + ty * 2 + i;
        #pragma unroll
        for (int j = 0; j < 4; ++j)
            Mp[(size_t)e * D_MODEL + k0 + tx * 4 + j] = acc[i][j];
    }
}

// ---------------------------------------------------------------------------
// Kernel A2: combine 4 D-quarters -> M64, emit bf16 split Mh/Ml. grid 512x256,
// 4 elems/thread.
// ---------------------------------------------------------------------------
__global__ __launch_bounds__(256) void cw_combine(
    const double* __restrict__ Mpart, double* __restrict__ M64,
    unsigned short* __restrict__ Mh, unsigned short* __restrict__ Ml)
{
    const int i4 = ((int)blockIdx.x * 256 + (int)threadIdx.x) * 4;
    const double* p0 = Mpart;
    const double* p1 = Mpart + (size_t)NUM_EXPERTS * D_MODEL;
    const double* p2 = Mpart + (size_t)2 * NUM_EXPERTS * D_MODEL;
    const double* p3 = Mpart + (size_t)3 * NUM_EXPERTS * D_MODEL;
    unsigned short hi[4], lo[4];
    #pragma unroll
    for (int u = 0; u < 4; ++u) {
        const double v = (p0[i4 + u] + p1[i4 + u]) + (p2[i4 + u] + p3[i4 + u]);
        M64[i4 + u] = v;
        const float f = (float)v;
        hi[u] = bf16_rne(f);
        lo[u] = bf16_rne(f - bf16_f32(hi[u]));
    }
    uint2 wh, wl;
    wh.x = (unsigned)hi[0] | ((unsigned)hi[1] << 16);
    wh.y = (unsigned)hi[2] | ((unsigned)hi[3] << 16);
    wl.x = (unsigned)lo[0] | ((unsigned)lo[1] << 16);
    wl.y = (unsigned)lo[2] | ((unsigned)lo[3] << 16);
    *(uint2*)(Mh + i4) = wh;
    *(uint2*)(Ml + i4) = wl;
}

// ---------------------------------------------------------------------------
// Kernel B: affinities via bf16-split MFMA (hh+hl+lh, f32 acc).
// tile 32t x 128e, BK=32, grid (512,2) = 1024 blocks (4/CU, 4 waves/SIMD).
// LDS in MFMA-fragment order (lane-sequential 16B, conflict-free).
// H staged via registers (needs split); M staged via global_load_lds (async,
// no VALU, completion guaranteed by the vmcnt(0) drain at __syncthreads).
// ---------------------------------------------------------------------------
__global__ __launch_bounds__(256, 4) void affinity_mfma(
    const float* __restrict__ H, const unsigned short* __restrict__ Mh,
    const unsigned short* __restrict__ Ml,
    float* __restrict__ aff, float* __restrict__ colsumPart)
{
    // fragment-order tiles: H 2 tiles x 64 lanes x 8 shorts; M 8 tiles.
    __shared__ unsigned short sHh[2][1024], sHl[2][1024];
    __shared__ unsigned short sMh[2][4096], sMl[2][4096];

    const int tid = threadIdx.x;
    const int lane = tid & 63, wv = tid >> 6;
    const int m = lane & 15, quad = lane >> 4;
    const int t0 = (int)blockIdx.x * 32;
    const int e0 = (int)blockIdx.y * 128;

    const int grp = tid >> 6;        // wave id 0..3
    const int q   = (tid >> 4) & 3;  // k-octet
    const int m16 = tid & 15;

    f32x4 acc[2][2];
    #pragma unroll
    for (int i = 0; i < 2; ++i)
        #pragma unroll
        for (int j = 0; j < 2; ++j) acc[i][j] = (f32x4){0.f, 0.f, 0.f, 0.f};

    float4 RA0, RA1, RB0, RB1;   // H prefetch regs (waves 0,1 only)

    auto loadH = [&](int kc, float4& A, float4& B) {
        if (grp < 2) {
            const int kb = kc * 32 + q * 8;
            const float* hp = H + (size_t)(t0 + grp * 16 + m16) * D_MODEL + kb;
            A = *(const float4*)hp;
            B = *(const float4*)(hp + 4);
        }
    };
    auto stageH = [&](int b, const float4& A, const float4& B) {
        if (grp < 2) {
            float x[8] = {A.x, A.y, A.z, A.w, B.x, B.y, B.z, B.w};
            unsigned short hi[8], lo[8];
            #pragma unroll
            for (int u = 0; u < 8; ++u) {
                hi[u] = bf16_rne(x[u]);
                lo[u] = bf16_rne(x[u] - bf16_f32(hi[u]));
            }
            uint4 ph, pl;
            ph.x = (unsigned)hi[0] | ((unsigned)hi[1] << 16);
            ph.y = (unsigned)hi[2] | ((unsigned)hi[3] << 16);
            ph.z = (unsigned)hi[4] | ((unsigned)hi[5] << 16);
            ph.w = (unsigned)hi[6] | ((unsigned)hi[7] << 16);
            pl.x = (unsigned)lo[0] | ((unsigned)lo[1] << 16);
            pl.y = (unsigned)lo[2] | ((unsigned)lo[3] << 16);
            pl.z = (unsigned)lo[4] | ((unsigned)lo[5] << 16);
            pl.w = (unsigned)lo[6] | ((unsigned)lo[7] << 16);
            *(uint4*)&sHh[b][grp * 512 + lane * 8] = ph;
            *(uint4*)&sHl[b][grp * 512 + lane * 8] = pl;
        }
    };
    auto gldsM = [&](int kc, int b) {
        const int kb = kc * 32 + q * 8;
        #pragma unroll
        for (int s = 0; s < 2; ++s) {
            const int e = e0 + (grp * 2 + s) * 16 + m16;
            const size_t g = (size_t)e * D_MODEL + kb;
            glds16(Mh + g, &sMh[b][(grp * 2 + s) * 512]);
            glds16(Ml + g, &sMl[b][(grp * 2 + s) * 512]);
        }
    };
    auto mfmaT = [&](int b) {
        short8 ah[2], al[2], bh[2], bl[2];
        #pragma unroll
        for (int i = 0; i < 2; ++i) {
            ah[i] = *(const short8*)&sHh[b][i * 512 + lane * 8];
            al[i] = *(const short8*)&sHl[b][i * 512 + lane * 8];
        }
        #pragma unroll
        for (int j = 0; j < 2; ++j) {
            bh[j] = *(const short8*)&sMh[b][(wv * 2 + j) * 512 + lane * 8];
            bl[j] = *(const short8*)&sMl[b][(wv * 2 + j) * 512 + lane * 8];
        }
        #pragma unroll
        for (int i = 0; i < 2; ++i)
            #pragma unroll
            for (int j = 0; j < 2; ++j) {
                acc[i][j] = __builtin_amdgcn_mfma_f32_16x16x32_bf16(ah[i], bh[j], acc[i][j], 0, 0, 0);
                acc[i][j] = __builtin_amdgcn_mfma_f32_16x16x32_bf16(ah[i], bl[j], acc[i][j], 0, 0, 0);
                acc[i][j] = __builtin_amdgcn_mfma_f32_16x16x32_bf16(al[i], bh[j], acc[i][j], 0, 0, 0);
            }
    };

    loadH(0, RA0, RA1);
    stageH(0, RA0, RA1);
    gldsM(0, 0);
    loadH(1, RB0, RB1);
    __syncthreads();                          // drains glds chunk 0

    for (int kc = 0; kc < 64; kc += 2) {
        stageH(1, RB0, RB1);                  // chunk kc+1 H -> buf1
        gldsM(kc + 1, 1);                     // chunk kc+1 M -> buf1 (async)
        if (kc + 2 < 64) loadH(kc + 2, RA0, RA1);
        mfmaT(0);                             // chunk kc
        __syncthreads();                      // vmcnt(0)+barrier: buf1 ready
        if (kc + 2 < 64) { stageH(0, RA0, RA1); gldsM(kc + 2, 0); }
        if (kc + 3 < 64) loadH(kc + 3, RB0, RB1);
        mfmaT(1);                             // chunk kc+1
        __syncthreads();
    }

    // epilogue: aff stores + sigmoid column partial sums (no atomics)
    #pragma unroll
    for (int j = 0; j < 2; ++j) {
        const int el = wv * 32 + j * 16 + m;   // local expert in [0,128)
        const int e = e0 + el;
        float colsum = 0.f;
        #pragma unroll
        for (int i = 0; i < 2; ++i) {
            const int tbase = t0 + i * 16 + quad * 4;
            #pragma unroll
            for (int r = 0; r < 4; ++r) {
                const float v = acc[i][j][r];
                aff[(size_t)(tbase + r) * NUM_EXPERTS + e] = v;
                colsum += 1.f / (1.f + expf(-v));
            }
        }
        colsum += __shfl_xor(colsum, 16, 64);
        colsum += __shfl_xor(colsum, 32, 64);
        if (quad == 0)
            colsumPart[((size_t)blockIdx.y * 512 + blockIdx.x) * 128 + el] = colsum;
    }
}

// ---------------------------------------------------------------------------
// Kernel C: fast top-9 (f32) on packed u64 keys + margin test.
// ---------------------------------------------------------------------------
__global__ __launch_bounds__(256) void topk_margin(
    const float* __restrict__ aff, const float* __restrict__ bias,
    float* __restrict__ out_idx, float* __restrict__ out_w,
    int* __restrict__ nmarg, int* __restrict__ list,
    int* __restrict__ ncand, int* __restrict__ cand)
{
    const int lane = threadIdx.x & 63;
    const int wv = threadIdx.x >> 6;
    const int t = blockIdx.x * 4 + wv;

    const float4 av = *(const float4*)(aff + (size_t)t * NUM_EXPERTS + lane * 4);
    const float4 bv = *(const float4*)(bias + lane * 4);
    float g[4], s0[4];
    g[0] = 1.f / (1.f + expf(-av.x)); s0[0] = g[0] + bv.x;
    g[1] = 1.f / (1.f + expf(-av.y)); s0[1] = g[1] + bv.y;
    g[2] = 1.f / (1.f + expf(-av.z)); s0[2] = g[2] + bv.z;
    g[3] = 1.f / (1.f + expf(-av.w)); s0[3] = g[3] + bv.w;

    unsigned long long kw[4];
    #pragma unroll
    for (int j = 0; j < 4; ++j)
        kw[j] = ((unsigned long long)ford(s0[j]) << 32)
              | (unsigned long long)(0xFFFFFFFFu - (unsigned)(lane * 4 + j));

    float wsum = 0.f, my_g = 0.f, prevs = 0.f, minGap = 1e30f, s8 = 0.f;
    int my_i = 0;

    #pragma unroll
    for (int it = 0; it < 9; ++it) {
        unsigned long long bk = kw[0];
        if (kw[1] > bk) bk = kw[1];
        if (kw[2] > bk) bk = kw[2];
        if (kw[3] > bk) bk = kw[3];
        #pragma unroll
        for (int off = 1; off < 64; off <<= 1) {
            const unsigned long long ok = __shfl_xor(bk, off, 64);
            if (ok > bk) bk = ok;
        }
        const unsigned o = (unsigned)(bk >> 32);
        const float sv = finv(o);
        const int e = (int)(0xFFFFFFFFu - (unsigned)(bk & 0xFFFFFFFFu));
        const int ej = e & 3, el = e >> 2;
        const float gl = (ej == 0) ? g[0] : (ej == 1) ? g[1] : (ej == 2) ? g[2] : g[3];
        const float gv = __shfl(gl, el, 64);
        if (it < TOP_K) {
            wsum += gv;
            if (lane == it) { my_i = e; my_g = gv; }
            if (it == 7) s8 = sv;
        }
        if (it > 0) minGap = fminf(minGap, prevs - sv);
        prevs = sv;
        if (lane == el) {
            if (ej == 0) kw[0] = 0ull; else if (ej == 1) kw[1] = 0ull;
            else if (ej == 2) kw[2] = 0ull; else kw[3] = 0ull;
        }
    }

    if (minGap < MARGIN) {
        int pos = 0;
        if (lane == 0) pos = atomicAdd(nmarg, 1);
        pos = __shfl(pos, 0, 64);
        const float thresh = s8 - MARGIN;
        int base = 0;
        #pragma unroll
        for (int j = 0; j < 4; ++j) {
            const bool c = (s0[j] >= thresh);
            const unsigned long long mk = __ballot(c);
            const int mypos = base + __popcll(mk & ((1ull << lane) - 1ull));
            if (c && mypos < 64) cand[(size_t)pos * 64 + mypos] = lane * 4 + j;
            base += (int)__popcll(mk);
        }
        if (lane == 0) { list[pos] = t; ncand[pos] = min(base, 64); }
    } else {
        const float inv = 1.f / (wsum + 1e-10f);
        if (lane < TOP_K) {
            out_idx[(size_t)t * TOP_K + lane] = (float)my_i;
            out_w[(size_t)t * TOP_K + lane] = my_g * inv;
        }
    }
}

// ---------------------------------------------------------------------------
// Kernel R: candidate-set f64 recheck.
// ---------------------------------------------------------------------------
__global__ __launch_bounds__(256) void recheck2(
    const float* __restrict__ H, const double* __restrict__ M64,
    const float* __restrict__ bias, const int* __restrict__ list,
    const int* __restrict__ ncand, const int* __restrict__ cand,
    const int* __restrict__ nmarg, float* __restrict__ out_idx,
    float* __restrict__ out_w)
{
    __shared__ float hsf[D_MODEL];
    __shared__ double sg[64], ssc[64];

    const int n = *nmarg;
    const int lane = threadIdx.x & 63, wv = threadIdx.x >> 6;

    for (int i = (int)blockIdx.x; i < n; i += (int)gridDim.x) {
        const int t = list[i];
        const int nc = ncand[i];

        for (int qd = threadIdx.x; qd < D_MODEL / 4; qd += 256)
            *(float4*)&hsf[qd * 4] = *(const float4*)(H + (size_t)t * D_MODEL + qd * 4);
        __syncthreads();

        for (int c = wv; c < nc; c += 4) {
            const int e = cand[(size_t)i * 64 + c];
            const double* mrow = M64 + (size_t)e * D_MODEL;
            double acc = 0.0;
            #pragma unroll 8
            for (int j = 0; j < 32; ++j) {
                const int k = lane + 64 * j;
                acc = fma((double)hsf[k], mrow[k], acc);
            }
            #pragma unroll
            for (int off = 1; off < 64; off <<= 1) acc += __shfl_xor(acc, off, 64);
            if (lane == 0) {
                const double gg = 1.0 / (1.0 + exp(-acc));
                sg[c] = gg;
                ssc[c] = gg + (double)bias[e];
            }
        }
        __syncthreads();

        if (wv == 0) {
            double s = -1e300, g = 0.0;
            int id = 1 << 20;
            if (lane < nc) { s = ssc[lane]; g = sg[lane]; id = cand[(size_t)i * 64 + lane]; }

            double wsum = 0.0, my_g = 0.0;
            int my_i = 0;
            for (int it = 0; it < TOP_K; ++it) {
                double bs = s, bg = g; int bi = id;
                #pragma unroll
                for (int off = 1; off < 64; off <<= 1) {
                    const double os = __shfl_xor(bs, off, 64);
                    const double og = __shfl_xor(bg, off, 64);
                    const int    oi = __shfl_xor(bi, off, 64);
                    if (os > bs || (os == bs && oi < bi)) { bs = os; bg = og; bi = oi; }
                }
                wsum += bg;
                if (lane == it) { my_i = bi; my_g = bg; }
                if (id == bi) s = -1e300;
            }
            const double inv = 1.0 / (wsum + 1e-10);
            if (lane < TOP_K) {
                out_idx[(size_t)t * TOP_K + lane] = (float)my_i;
                out_w[(size_t)t * TOP_K + lane] = (float)(my_g * inv);
            }
        }
        __syncthreads();
    }
}

// ---------------------------------------------------------------------------
// Kernel H: histogram out_idx -> counts; reduce colsumPart -> sumP.
// grid 64 x 256. colsumPart is now [2][512][128].
// ---------------------------------------------------------------------------
__global__ __launch_bounds__(256) void hist_reduce(
    const float* __restrict__ out_idx, const float* __restrict__ colsumPart,
    int* __restrict__ counts, double* __restrict__ sumP)
{
    __shared__ int h[NUM_EXPERTS];
    const int tid = threadIdx.x;
    const int lane = tid & 63, wv = tid >> 6;
    h[tid] = 0;
    __syncthreads();
    for (int i = (int)blockIdx.x * 256 + tid; i < T_TOKENS * TOP_K; i += 64 * 256)
        atomicAdd(&h[(int)out_idx[i]], 1);
    __syncthreads();
    if (h[tid] != 0) atomicAdd(&counts[tid], h[tid]);

    const int e = (int)blockIdx.x * 4 + wv;
    const int half = e >> 7, el = e & 127;
    float ps = 0.f;
    for (int p = lane; p < 512; p += 64)
        ps += colsumPart[((size_t)half * 512 + p) * 128 + el];
    #pragma unroll
    for (int off = 1; off < 64; off <<= 1) ps += __shfl_xor(ps, off, 64);
    if (lane == 0) sumP[e] = (double)ps;
}

// ---------------------------------------------------------------------------
// Kernel D: balance loss
// ---------------------------------------------------------------------------
__global__ __launch_bounds__(256) void loss_f64(
    const double* __restrict__ sumP, const int* __restrict__ counts,
    float* __restrict__ out_loss)
{
    __shared__ double red[256];
    const int e = threadIdx.x;
    red[e] = (double)counts[e] * sumP[e];
    __syncthreads();
    #pragma unroll
    for (int sft = 128; sft > 0; sft >>= 1) {
        if (e < sft) red[e] += red[e + sft];
        __syncthreads();
    }
    if (e == 0) {
        const double denom = (double)T_TOKENS * (double)TOP_K * (double)T_TOKENS;
        out_loss[0] = (float)(0.001 * ((double)NUM_EXPERTS / (double)TOP_K) * red[0] / denom);
    }
}

extern "C" void kernel_launch(void* const* d_in, const int* in_sizes, int n_in,
                              void* d_out, int out_size, void* d_ws, size_t ws_size,
                              hipStream_t stream) {
    (void)in_sizes; (void)n_in; (void)out_size; (void)ws_size;
    const float* hidden = (const float*)d_in[0];
    const float* W      = (const float*)d_in[1];
    const float* C      = (const float*)d_in[2];
    const float* bias   = (const float*)d_in[3];
    float* out = (float*)d_out;
    char* ws   = (char*)d_ws;

    double*         M64    = (double*)(ws + WS_M64_B);
    unsigned short* Mh     = (unsigned short*)(ws + WS_MH_B);
    unsigned short* Ml     = (unsigned short*)(ws + WS_ML_B);
    double*         sumP   = (double*)(ws + WS_SUMP_B);
    int*            counts = (int*)(ws + WS_CNT_B);
    int*            nmarg  = (int*)(ws + WS_NMARG_B);
    int*            list   = (int*)(ws + WS_LIST_B);
    int*            ncand  = (int*)(ws + WS_NCAND_B);
    int*            cand   = (int*)(ws + WS_CAND_B);
    float*          csp    = (float*)(ws + WS_CSP_B);
    double*         Mpart  = (double*)(ws + WS_MP_B);

    hipMemsetAsync(ws + WS_CNT_B, 0, NUM_EXPERTS * 4 + 16, stream);

    cw_gemm_part<<<dim3(D_MODEL / 64, NUM_EXPERTS / 32, 4), 256, 0, stream>>>(C, W, Mpart);
    cw_combine<<<dim3(NUM_EXPERTS * D_MODEL / 1024), 256, 0, stream>>>(Mpart, M64, Mh, Ml);

    affinity_mfma<<<dim3(T_TOKENS / 32, 2), 256, 0, stream>>>(hidden, Mh, Ml, out + OUT_AFF, csp);

    topk_margin<<<dim3(T_TOKENS / 4), 256, 0, stream>>>(
        out + OUT_AFF, bias, out + OUT_IDX, out + OUT_W, nmarg, list, ncand, cand);

    recheck2<<<dim3(2048), 256, 0, stream>>>(
        hidden, M64, bias, list, ncand, cand, nmarg, out + OUT_IDX, out + OUT_W);

    hist_reduce<<<dim3(64), 256, 0, stream>>>(out + OUT_IDX, csp, counts, sumP);

    loss_f64<<<dim3(1), 256, 0, stream>>>(sumP, counts, out + OUT_LOSS);
}

// Round 2
// 437.674 us; speedup vs baseline: 1.0376x; 1.0376x over previous
//
#include <hip/hip_runtime.h>
#include <math.h>

#define T_TOKENS    16384
#define D_MODEL     2048
#define NUM_EXPERTS 256
#define TOP_K       8
#define MARGIN      6e-5f

// d_out layout (floats): idx | weights | affinities | loss
#define OUT_IDX  0
#define OUT_W    (T_TOKENS * TOP_K)
#define OUT_AFF  (2 * T_TOKENS * TOP_K)
#define OUT_LOSS (2 * T_TOKENS * TOP_K + T_TOKENS * NUM_EXPERTS)

// ws layout (bytes)
#define WS_M64_B   ((size_t)0)                                    // double[256*2048] 4MB
#define WS_MH_B    (WS_M64_B + (size_t)NUM_EXPERTS * D_MODEL * 8) // bf16 1MB
#define WS_ML_B    (WS_MH_B  + (size_t)NUM_EXPERTS * D_MODEL * 2) // bf16 1MB
#define WS_SUMP_B  (WS_ML_B  + (size_t)NUM_EXPERTS * D_MODEL * 2) // double[256]
#define WS_CNT_B   (WS_SUMP_B + NUM_EXPERTS * 8)                  // int[256]
#define WS_NMARG_B (WS_CNT_B  + NUM_EXPERTS * 4)                  // int (+pad)
#define WS_LIST_B  (WS_NMARG_B + 16)                              // int[16384]
#define WS_NCAND_B (WS_LIST_B + (size_t)T_TOKENS * 4)             // int[16384]
#define WS_CAND_B  (WS_NCAND_B + (size_t)T_TOKENS * 4)            // int[16384*64] 4MB
#define WS_CSP_B   (WS_CAND_B + (size_t)T_TOKENS * 64 * 4)        // float[4096*256] 4MB
// Mpart (double[4][256*2048] = 16MB, live A1->A2) exactly aliases
// paff1 (float[16384*256] = 16MB, live affinity->topk). Disjoint lifetimes.
#define WS_MP_B    (WS_CSP_B + (size_t)4096 * 256 * 4)

typedef __attribute__((ext_vector_type(8))) short short8;
typedef __attribute__((ext_vector_type(4))) float f32x4;

__device__ __forceinline__ unsigned short bf16_rne(float x) {
    unsigned u = __float_as_uint(x);
    u += 0x7FFFu + ((u >> 16) & 1u);
    return (unsigned short)(u >> 16);
}
__device__ __forceinline__ float bf16_f32(unsigned short h) {
    return __uint_as_float(((unsigned)h) << 16);
}
__device__ __forceinline__ unsigned ford(float f) {
    unsigned u = __float_as_uint(f);
    return ((int)u >= 0) ? (u | 0x80000000u) : ~u;
}
__device__ __forceinline__ float finv(unsigned o) {
    return (o & 0x80000000u) ? __uint_as_float(o ^ 0x80000000u)
                             : __uint_as_float(~o);
}
// async global->LDS, 16B per lane; LDS dest = wave-uniform base + lane*16
__device__ __forceinline__ void glds16(const void* g, void* l) {
    __builtin_amdgcn_global_load_lds(
        (const __attribute__((address_space(1))) unsigned int*)g,
        (__attribute__((address_space(3))) unsigned int*)l,
        16, 0, 0);
}

// ---------------------------------------------------------------------------
// Kernel A1: partial M = C @ W over a D-quarter. tile 32e x 64k, grid (32,8,4)
// = 1024 blocks (4 blocks/CU -> 16 waves/CU for latency hiding).
// ---------------------------------------------------------------------------
__global__ __launch_bounds__(256, 4) void cw_gemm_part(
    const float* __restrict__ C, const float* __restrict__ W,
    double* __restrict__ Mpart)
{
    __shared__ float Cs[32][34];
    __shared__ float Ws[32][68];

    const int tid = threadIdx.x;
    const int tx = tid & 15;
    const int ty = tid >> 4;
    const int e0 = blockIdx.y * 32;
    const int k0 = blockIdx.x * 64;
    const int z  = blockIdx.z;

    double* Mp = Mpart + (size_t)z * NUM_EXPERTS * D_MODEL;
    double acc[2][4] = {{0,0,0,0},{0,0,0,0}};

    for (int d0 = z * 512; d0 < (z + 1) * 512; d0 += 32) {
        {
            const int e = tid >> 3, d4 = (tid & 7) * 4;
            const float4 v = *(const float4*)(C + (size_t)(e0 + e) * D_MODEL + d0 + d4);
            Cs[d4 + 0][e] = v.x; Cs[d4 + 1][e] = v.y;
            Cs[d4 + 2][e] = v.z; Cs[d4 + 3][e] = v.w;
        }
        #pragma unroll
        for (int r = 0; r < 2; ++r) {
            const int idx = tid + r * 256;
            const int d = idx >> 4, k4 = (idx & 15) * 4;
            *(float4*)&Ws[d][k4] =
                *(const float4*)(W + (size_t)(d0 + d) * D_MODEL + k0 + k4);
        }
        __syncthreads();
        #pragma unroll
        for (int dd = 0; dd < 32; ++dd) {
            const float2 a2 = *(const float2*)&Cs[dd][ty * 2];
            const double a0 = (double)a2.x, a1 = (double)a2.y;
            const float4 b4 = *(const float4*)&Ws[dd][tx * 4];
            const double b[4] = {(double)b4.x, (double)b4.y, (double)b4.z, (double)b4.w};
            #pragma unroll
            for (int j = 0; j < 4; ++j) { acc[0][j] += a0 * b[j]; acc[1][j] += a1 * b[j]; }
        }
        __syncthreads();
    }
    #pragma unroll
    for (int i = 0; i < 2; ++i) {
        const int e = e0 + ty * 2 + i;
        #pragma unroll
        for (int j = 0; j < 4; ++j)
            Mp[(size_t)e * D_MODEL + k0 + tx * 4 + j] = acc[i][j];
    }
}

// ---------------------------------------------------------------------------
// Kernel A2: combine 4 D-quarters -> M64, emit bf16 split Mh/Ml. grid 512x256,
// 4 elems/thread.
// ---------------------------------------------------------------------------
__global__ __launch_bounds__(256) void cw_combine(
    const double* __restrict__ Mpart, double* __restrict__ M64,
    unsigned short* __restrict__ Mh, unsigned short* __restrict__ Ml)
{
    const int i4 = ((int)blockIdx.x * 256 + (int)threadIdx.x) * 4;
    const double* p0 = Mpart;
    const double* p1 = Mpart + (size_t)NUM_EXPERTS * D_MODEL;
    const double* p2 = Mpart + (size_t)2 * NUM_EXPERTS * D_MODEL;
    const double* p3 = Mpart + (size_t)3 * NUM_EXPERTS * D_MODEL;
    unsigned short hi[4], lo[4];
    #pragma unroll
    for (int u = 0; u < 4; ++u) {
        const double v = (p0[i4 + u] + p1[i4 + u]) + (p2[i4 + u] + p3[i4 + u]);
        M64[i4 + u] = v;
        const float f = (float)v;
        hi[u] = bf16_rne(f);
        lo[u] = bf16_rne(f - bf16_f32(hi[u]));
    }
    uint2 wh, wl;
    wh.x = (unsigned)hi[0] | ((unsigned)hi[1] << 16);
    wh.y = (unsigned)hi[2] | ((unsigned)hi[3] << 16);
    wl.x = (unsigned)lo[0] | ((unsigned)lo[1] << 16);
    wl.y = (unsigned)lo[2] | ((unsigned)lo[3] << 16);
    *(uint2*)(Mh + i4) = wh;
    *(uint2*)(Ml + i4) = wl;
}

// ---------------------------------------------------------------------------
// Kernel B: affinity partials via bf16-split MFMA (hh+hl+lh, f32 acc).
// tile 64t x 128e, BK=32, K-split in 2 halves via blockIdx.z.
// grid (256,2,2) = 1024 blocks, 48KB LDS -> 3 blocks/CU (12 waves/CU).
// LDS in MFMA-fragment order (lane-sequential 16B, conflict-free).
// H staged via registers (needs bf16 split); M via global_load_lds (async).
// z=0 partial -> aff output region; z=1 partial -> paff1 (ws).
// ---------------------------------------------------------------------------
__global__ __launch_bounds__(256, 3) void affinity_mfma(
    const float* __restrict__ H, const unsigned short* __restrict__ Mh,
    const unsigned short* __restrict__ Ml,
    float* __restrict__ paff0, float* __restrict__ paff1)
{
    // fragment-order tiles: H 4 tiles x 64 lanes x 8 shorts; M 8 tiles.
    __shared__ unsigned short sHh[2][2048], sHl[2][2048];
    __shared__ unsigned short sMh[2][4096], sMl[2][4096];

    const int tid = threadIdx.x;
    const int lane = tid & 63, wv = tid >> 6;
    const int m = lane & 15, quad = lane >> 4;
    const int t0 = (int)blockIdx.x * 64;
    const int e0 = (int)blockIdx.y * 128;
    const int zb = (int)blockIdx.z * 32;      // K-chunk base (32 chunks each)

    const int grp = tid >> 6;        // wave id 0..3
    const int q   = (tid >> 4) & 3;  // k-octet
    const int m16 = tid & 15;

    f32x4 acc[4][2];
    #pragma unroll
    for (int i = 0; i < 4; ++i)
        #pragma unroll
        for (int j = 0; j < 2; ++j) acc[i][j] = (f32x4){0.f, 0.f, 0.f, 0.f};

    float4 RA0, RA1, RB0, RB1;   // H prefetch regs

    auto loadH = [&](int kc, float4& A, float4& B) {
        const int kb = (zb + kc) * 32 + q * 8;
        const float* hp = H + (size_t)(t0 + grp * 16 + m16) * D_MODEL + kb;
        A = *(const float4*)hp;
        B = *(const float4*)(hp + 4);
    };
    auto stageH = [&](int b, const float4& A, const float4& B) {
        float x[8] = {A.x, A.y, A.z, A.w, B.x, B.y, B.z, B.w};
        unsigned short hi[8], lo[8];
        #pragma unroll
        for (int u = 0; u < 8; ++u) {
            hi[u] = bf16_rne(x[u]);
            lo[u] = bf16_rne(x[u] - bf16_f32(hi[u]));
        }
        uint4 ph, pl;
        ph.x = (unsigned)hi[0] | ((unsigned)hi[1] << 16);
        ph.y = (unsigned)hi[2] | ((unsigned)hi[3] << 16);
        ph.z = (unsigned)hi[4] | ((unsigned)hi[5] << 16);
        ph.w = (unsigned)hi[6] | ((unsigned)hi[7] << 16);
        pl.x = (unsigned)lo[0] | ((unsigned)lo[1] << 16);
        pl.y = (unsigned)lo[2] | ((unsigned)lo[3] << 16);
        pl.z = (unsigned)lo[4] | ((unsigned)lo[5] << 16);
        pl.w = (unsigned)lo[6] | ((unsigned)lo[7] << 16);
        *(uint4*)&sHh[b][grp * 512 + lane * 8] = ph;
        *(uint4*)&sHl[b][grp * 512 + lane * 8] = pl;
    };
    auto gldsM = [&](int kc, int b) {
        const int kb = (zb + kc) * 32 + q * 8;
        #pragma unroll
        for (int s = 0; s < 2; ++s) {
            const int e = e0 + (grp * 2 + s) * 16 + m16;
            const size_t g = (size_t)e * D_MODEL + kb;
            glds16(Mh + g, &sMh[b][(grp * 2 + s) * 512]);
            glds16(Ml + g, &sMl[b][(grp * 2 + s) * 512]);
        }
    };
    auto mfmaT = [&](int b) {
        short8 ah[4], al[4], bh[2], bl[2];
        #pragma unroll
        for (int i = 0; i < 4; ++i) {
            ah[i] = *(const short8*)&sHh[b][i * 512 + lane * 8];
            al[i] = *(const short8*)&sHl[b][i * 512 + lane * 8];
        }
        #pragma unroll
        for (int j = 0; j < 2; ++j) {
            bh[j] = *(const short8*)&sMh[b][(wv * 2 + j) * 512 + lane * 8];
            bl[j] = *(const short8*)&sMl[b][(wv * 2 + j) * 512 + lane * 8];
        }
        #pragma unroll
        for (int i = 0; i < 4; ++i)
            #pragma unroll
            for (int j = 0; j < 2; ++j) {
                acc[i][j] = __builtin_amdgcn_mfma_f32_16x16x32_bf16(ah[i], bh[j], acc[i][j], 0, 0, 0);
                acc[i][j] = __builtin_amdgcn_mfma_f32_16x16x32_bf16(ah[i], bl[j], acc[i][j], 0, 0, 0);
                acc[i][j] = __builtin_amdgcn_mfma_f32_16x16x32_bf16(al[i], bh[j], acc[i][j], 0, 0, 0);
            }
    };

    loadH(0, RA0, RA1);
    stageH(0, RA0, RA1);
    gldsM(0, 0);
    loadH(1, RB0, RB1);
    __syncthreads();                          // drains glds chunk 0

    for (int kc = 0; kc < 32; kc += 2) {
        stageH(1, RB0, RB1);                  // chunk kc+1 H -> buf1
        gldsM(kc + 1, 1);                     // chunk kc+1 M -> buf1 (async)
        if (kc + 2 < 32) loadH(kc + 2, RA0, RA1);
        mfmaT(0);                             // chunk kc
        __syncthreads();                      // vmcnt(0)+barrier: buf1 ready
        if (kc + 2 < 32) { stageH(0, RA0, RA1); gldsM(kc + 2, 0); }
        if (kc + 3 < 32) loadH(kc + 3, RB0, RB1);
        mfmaT(1);                             // chunk kc+1
        __syncthreads();
    }

    // epilogue: store f32 partial tile (no sigmoid here; topk combines)
    float* pz = (blockIdx.z == 0) ? paff0 : paff1;
    #pragma unroll
    for (int j = 0; j < 2; ++j) {
        const int e = e0 + wv * 32 + j * 16 + m;
        #pragma unroll
        for (int i = 0; i < 4; ++i) {
            const int tbase = t0 + i * 16 + quad * 4;
            #pragma unroll
            for (int r = 0; r < 4; ++r)
                pz[(size_t)(tbase + r) * NUM_EXPERTS + e] = acc[i][j][r];
        }
    }
}

// ---------------------------------------------------------------------------
// Kernel C: combine K-split partials -> aff, sigmoid colsum partials,
// fast top-9 (f32) on packed u64 keys + margin test. grid 4096 x 256.
// ---------------------------------------------------------------------------
__global__ __launch_bounds__(256) void topk_margin(
    const float* __restrict__ paff0, const float* __restrict__ paff1,
    const float* __restrict__ bias,
    float* __restrict__ aff, float* __restrict__ csp,
    float* __restrict__ out_idx, float* __restrict__ out_w,
    int* __restrict__ nmarg, int* __restrict__ list,
    int* __restrict__ ncand, int* __restrict__ cand)
{
    __shared__ float sg4[4][NUM_EXPERTS];

    const int tid = threadIdx.x;
    const int lane = tid & 63;
    const int wv = tid >> 6;
    const int t = blockIdx.x * 4 + wv;

    const float4 a0 = *(const float4*)(paff0 + (size_t)t * NUM_EXPERTS + lane * 4);
    const float4 a1 = *(const float4*)(paff1 + (size_t)t * NUM_EXPERTS + lane * 4);
    float4 av;
    av.x = a0.x + a1.x; av.y = a0.y + a1.y;
    av.z = a0.z + a1.z; av.w = a0.w + a1.w;
    *(float4*)(aff + (size_t)t * NUM_EXPERTS + lane * 4) = av;

    const float4 bv = *(const float4*)(bias + lane * 4);
    float g[4], s0[4];
    g[0] = 1.f / (1.f + expf(-av.x)); s0[0] = g[0] + bv.x;
    g[1] = 1.f / (1.f + expf(-av.y)); s0[1] = g[1] + bv.y;
    g[2] = 1.f / (1.f + expf(-av.z)); s0[2] = g[2] + bv.z;
    g[3] = 1.f / (1.f + expf(-av.w)); s0[3] = g[3] + bv.w;

    // per-block sigmoid column partial (all tokens, unconditional)
    *(float4*)&sg4[wv][lane * 4] = *(float4*)g;
    __syncthreads();
    {
        const float s = sg4[0][tid] + sg4[1][tid] + sg4[2][tid] + sg4[3][tid];
        csp[(size_t)blockIdx.x * NUM_EXPERTS + tid] = s;
    }

    unsigned long long kw[4];
    #pragma unroll
    for (int j = 0; j < 4; ++j)
        kw[j] = ((unsigned long long)ford(s0[j]) << 32)
              | (unsigned long long)(0xFFFFFFFFu - (unsigned)(lane * 4 + j));

    float wsum = 0.f, my_g = 0.f, prevs = 0.f, minGap = 1e30f, s8 = 0.f;
    int my_i = 0;

    #pragma unroll
    for (int it = 0; it < 9; ++it) {
        unsigned long long bk = kw[0];
        if (kw[1] > bk) bk = kw[1];
        if (kw[2] > bk) bk = kw[2];
        if (kw[3] > bk) bk = kw[3];
        #pragma unroll
        for (int off = 1; off < 64; off <<= 1) {
            const unsigned long long ok = __shfl_xor(bk, off, 64);
            if (ok > bk) bk = ok;
        }
        const unsigned o = (unsigned)(bk >> 32);
        const float sv = finv(o);
        const int e = (int)(0xFFFFFFFFu - (unsigned)(bk & 0xFFFFFFFFu));
        const int ej = e & 3, el = e >> 2;
        const float gl = (ej == 0) ? g[0] : (ej == 1) ? g[1] : (ej == 2) ? g[2] : g[3];
        const float gv = __shfl(gl, el, 64);
        if (it < TOP_K) {
            wsum += gv;
            if (lane == it) { my_i = e; my_g = gv; }
            if (it == 7) s8 = sv;
        }
        if (it > 0) minGap = fminf(minGap, prevs - sv);
        prevs = sv;
        if (lane == el) {
            if (ej == 0) kw[0] = 0ull; else if (ej == 1) kw[1] = 0ull;
            else if (ej == 2) kw[2] = 0ull; else kw[3] = 0ull;
        }
    }

    if (minGap < MARGIN) {
        int pos = 0;
        if (lane == 0) pos = atomicAdd(nmarg, 1);
        pos = __shfl(pos, 0, 64);
        const float thresh = s8 - MARGIN;
        int base = 0;
        #pragma unroll
        for (int j = 0; j < 4; ++j) {
            const bool c = (s0[j] >= thresh);
            const unsigned long long mk = __ballot(c);
            const int mypos = base + __popcll(mk & ((1ull << lane) - 1ull));
            if (c && mypos < 64) cand[(size_t)pos * 64 + mypos] = lane * 4 + j;
            base += (int)__popcll(mk);
        }
        if (lane == 0) { list[pos] = t; ncand[pos] = min(base, 64); }
    } else {
        const float inv = 1.f / (wsum + 1e-10f);
        if (lane < TOP_K) {
            out_idx[(size_t)t * TOP_K + lane] = (float)my_i;
            out_w[(size_t)t * TOP_K + lane] = my_g * inv;
        }
    }
}

// ---------------------------------------------------------------------------
// Kernel R: candidate-set f64 recheck.
// ---------------------------------------------------------------------------
__global__ __launch_bounds__(256) void recheck2(
    const float* __restrict__ H, const double* __restrict__ M64,
    const float* __restrict__ bias, const int* __restrict__ list,
    const int* __restrict__ ncand, const int* __restrict__ cand,
    const int* __restrict__ nmarg, float* __restrict__ out_idx,
    float* __restrict__ out_w)
{
    __shared__ float hsf[D_MODEL];
    __shared__ double sg[64], ssc[64];

    const int n = *nmarg;
    const int lane = threadIdx.x & 63, wv = threadIdx.x >> 6;

    for (int i = (int)blockIdx.x; i < n; i += (int)gridDim.x) {
        const int t = list[i];
        const int nc = ncand[i];

        for (int qd = threadIdx.x; qd < D_MODEL / 4; qd += 256)
            *(float4*)&hsf[qd * 4] = *(const float4*)(H + (size_t)t * D_MODEL + qd * 4);
        __syncthreads();

        for (int c = wv; c < nc; c += 4) {
            const int e = cand[(size_t)i * 64 + c];
            const double* mrow = M64 + (size_t)e * D_MODEL;
            double acc = 0.0;
            #pragma unroll 8
            for (int j = 0; j < 32; ++j) {
                const int k = lane + 64 * j;
                acc = fma((double)hsf[k], mrow[k], acc);
            }
            #pragma unroll
            for (int off = 1; off < 64; off <<= 1) acc += __shfl_xor(acc, off, 64);
            if (lane == 0) {
                const double gg = 1.0 / (1.0 + exp(-acc));
                sg[c] = gg;
                ssc[c] = gg + (double)bias[e];
            }
        }
        __syncthreads();

        if (wv == 0) {
            double s = -1e300, g = 0.0;
            int id = 1 << 20;
            if (lane < nc) { s = ssc[lane]; g = sg[lane]; id = cand[(size_t)i * 64 + lane]; }

            double wsum = 0.0, my_g = 0.0;
            int my_i = 0;
            for (int it = 0; it < TOP_K; ++it) {
                double bs = s, bg = g; int bi = id;
                #pragma unroll
                for (int off = 1; off < 64; off <<= 1) {
                    const double os = __shfl_xor(bs, off, 64);
                    const double og = __shfl_xor(bg, off, 64);
                    const int    oi = __shfl_xor(bi, off, 64);
                    if (os > bs || (os == bs && oi < bi)) { bs = os; bg = og; bi = oi; }
                }
                wsum += bg;
                if (lane == it) { my_i = bi; my_g = bg; }
                if (id == bi) s = -1e300;
            }
            const double inv = 1.0 / (wsum + 1e-10);
            if (lane < TOP_K) {
                out_idx[(size_t)t * TOP_K + lane] = (float)my_i;
                out_w[(size_t)t * TOP_K + lane] = (float)(my_g * inv);
            }
        }
        __syncthreads();
    }
}

// ---------------------------------------------------------------------------
// Kernel H: histogram out_idx -> counts; reduce csp[4096][256] -> sumP.
// grid 64 x 256.
// ---------------------------------------------------------------------------
__global__ __launch_bounds__(256) void hist_reduce(
    const float* __restrict__ out_idx, const float* __restrict__ csp,
    int* __restrict__ counts, double* __restrict__ sumP)
{
    __shared__ int h[NUM_EXPERTS];
    const int tid = threadIdx.x;
    const int lane = tid & 63, wv = tid >> 6;
    h[tid] = 0;
    __syncthreads();
    for (int i = (int)blockIdx.x * 256 + tid; i < T_TOKENS * TOP_K; i += 64 * 256)
        atomicAdd(&h[(int)out_idx[i]], 1);
    __syncthreads();
    if (h[tid] != 0) atomicAdd(&counts[tid], h[tid]);

    const int e = (int)blockIdx.x * 4 + wv;
    float ps = 0.f;
    for (int p = lane; p < 4096; p += 64)
        ps += csp[(size_t)p * NUM_EXPERTS + e];
    #pragma unroll
    for (int off = 1; off < 64; off <<= 1) ps += __shfl_xor(ps, off, 64);
    if (lane == 0) sumP[e] = (double)ps;
}

// ---------------------------------------------------------------------------
// Kernel D: balance loss
// ---------------------------------------------------------------------------
__global__ __launch_bounds__(256) void loss_f64(
    const double* __restrict__ sumP, const int* __restrict__ counts,
    float* __restrict__ out_loss)
{
    __shared__ double red[256];
    const int e = threadIdx.x;
    red[e] = (double)counts[e] * sumP[e];
    __syncthreads();
    #pragma unroll
    for (int sft = 128; sft > 0; sft >>= 1) {
        if (e < sft) red[e] += red[e + sft];
        __syncthreads();
    }
    if (e == 0) {
        const double denom = (double)T_TOKENS * (double)TOP_K * (double)T_TOKENS;
        out_loss[0] = (float)(0.001 * ((double)NUM_EXPERTS / (double)TOP_K) * red[0] / denom);
    }
}

extern "C" void kernel_launch(void* const* d_in, const int* in_sizes, int n_in,
                              void* d_out, int out_size, void* d_ws, size_t ws_size,
                              hipStream_t stream) {
    (void)in_sizes; (void)n_in; (void)out_size; (void)ws_size;
    const float* hidden = (const float*)d_in[0];
    const float* W      = (const float*)d_in[1];
    const float* C      = (const float*)d_in[2];
    const float* bias   = (const float*)d_in[3];
    float* out = (float*)d_out;
    char* ws   = (char*)d_ws;

    double*         M64    = (double*)(ws + WS_M64_B);
    unsigned short* Mh     = (unsigned short*)(ws + WS_MH_B);
    unsigned short* Ml     = (unsigned short*)(ws + WS_ML_B);
    double*         sumP   = (double*)(ws + WS_SUMP_B);
    int*            counts = (int*)(ws + WS_CNT_B);
    int*            nmarg  = (int*)(ws + WS_NMARG_B);
    int*            list   = (int*)(ws + WS_LIST_B);
    int*            ncand  = (int*)(ws + WS_NCAND_B);
    int*            cand   = (int*)(ws + WS_CAND_B);
    float*          csp    = (float*)(ws + WS_CSP_B);
    double*         Mpart  = (double*)(ws + WS_MP_B);   // 16MB, dead after A2
    float*          paff1  = (float*)(ws + WS_MP_B);    // 16MB, alias (disjoint lifetime)

    hipMemsetAsync(ws + WS_CNT_B, 0, NUM_EXPERTS * 4 + 16, stream);

    cw_gemm_part<<<dim3(D_MODEL / 64, NUM_EXPERTS / 32, 4), 256, 0, stream>>>(C, W, Mpart);
    cw_combine<<<dim3(NUM_EXPERTS * D_MODEL / 1024), 256, 0, stream>>>(Mpart, M64, Mh, Ml);

    affinity_mfma<<<dim3(T_TOKENS / 64, 2, 2), 256, 0, stream>>>(
        hidden, Mh, Ml, out + OUT_AFF, paff1);

    topk_margin<<<dim3(T_TOKENS / 4), 256, 0, stream>>>(
        out + OUT_AFF, paff1, bias, out + OUT_AFF, csp,
        out + OUT_IDX, out + OUT_W, nmarg, list, ncand, cand);

    recheck2<<<dim3(2048), 256, 0, stream>>>(
        hidden, M64, bias, list, ncand, cand, nmarg, out + OUT_IDX, out + OUT_W);

    hist_reduce<<<dim3(64), 256, 0, stream>>>(out + OUT_IDX, csp, counts, sumP);

    loss_f64<<<dim3(1), 256, 0, stream>>>(sumP, counts, out + OUT_LOSS);
}

// Round 3
// 393.076 us; speedup vs baseline: 1.1554x; 1.1135x over previous
//
#include <hip/hip_runtime.h>
#include <math.h>

#define T_TOKENS    16384
#define D_MODEL     2048
#define NUM_EXPERTS 256
#define TOP_K       8
#define MARGIN      6e-5f

// d_out layout (floats): idx | weights | affinities | loss
#define OUT_IDX  0
#define OUT_W    (T_TOKENS * TOP_K)
#define OUT_AFF  (2 * T_TOKENS * TOP_K)
#define OUT_LOSS (2 * T_TOKENS * TOP_K + T_TOKENS * NUM_EXPERTS)

// ws layout (bytes)
#define WS_M64_B   ((size_t)0)                                    // double[256*2048] 4MB
#define WS_MH_B    (WS_M64_B + (size_t)NUM_EXPERTS * D_MODEL * 8) // bf16 1MB
#define WS_ML_B    (WS_MH_B  + (size_t)NUM_EXPERTS * D_MODEL * 2) // bf16 1MB
#define WS_SUMP_B  (WS_ML_B  + (size_t)NUM_EXPERTS * D_MODEL * 2) // double[256]
#define WS_CNT_B   (WS_SUMP_B + NUM_EXPERTS * 8)                  // int[256]
#define WS_NMARG_B (WS_CNT_B  + NUM_EXPERTS * 4)                  // int (+pad)
#define WS_LIST_B  (WS_NMARG_B + 16)                              // int[16384]
#define WS_NCAND_B (WS_LIST_B + (size_t)T_TOKENS * 4)             // int[16384]
#define WS_CAND_B  (WS_NCAND_B + (size_t)T_TOKENS * 4)            // int[16384*64] 4MB
#define WS_CSP_B   (WS_CAND_B + (size_t)T_TOKENS * 64 * 4)        // float[2*256*128] 256KB (slot 4MB)
#define WS_MP_B    (WS_CSP_B + (size_t)4096 * 256 * 4)            // double[4][256*2048] 16MB

typedef __attribute__((ext_vector_type(8))) short short8;
typedef __attribute__((ext_vector_type(4))) float f32x4;

__device__ __forceinline__ unsigned short bf16_rne(float x) {
    unsigned u = __float_as_uint(x);
    u += 0x7FFFu + ((u >> 16) & 1u);
    return (unsigned short)(u >> 16);
}
__device__ __forceinline__ float bf16_f32(unsigned short h) {
    return __uint_as_float(((unsigned)h) << 16);
}
__device__ __forceinline__ unsigned ford(float f) {
    unsigned u = __float_as_uint(f);
    return ((int)u >= 0) ? (u | 0x80000000u) : ~u;
}
__device__ __forceinline__ float finv(unsigned o) {
    return (o & 0x80000000u) ? __uint_as_float(o ^ 0x80000000u)
                             : __uint_as_float(~o);
}
// async global->LDS, 16B per lane; LDS dest = wave-uniform base + lane*16
__device__ __forceinline__ void glds16(const void* g, void* l) {
    __builtin_amdgcn_global_load_lds(
        (const __attribute__((address_space(1))) unsigned int*)g,
        (__attribute__((address_space(3))) unsigned int*)l,
        16, 0, 0);
}

// ---------------------------------------------------------------------------
// Kernel A1: partial M = C @ W over a D-quarter. tile 32e x 64k, grid (32,8,4)
// = 1024 blocks (4 blocks/CU for latency hiding).
// ---------------------------------------------------------------------------
__global__ __launch_bounds__(256, 4) void cw_gemm_part(
    const float* __restrict__ C, const float* __restrict__ W,
    double* __restrict__ Mpart)
{
    __shared__ float Cs[32][34];
    __shared__ float Ws[32][68];

    const int tid = threadIdx.x;
    const int tx = tid & 15;
    const int ty = tid >> 4;
    const int e0 = blockIdx.y * 32;
    const int k0 = blockIdx.x * 64;
    const int z  = blockIdx.z;

    double* Mp = Mpart + (size_t)z * NUM_EXPERTS * D_MODEL;
    double acc[2][4] = {{0,0,0,0},{0,0,0,0}};

    for (int d0 = z * 512; d0 < (z + 1) * 512; d0 += 32) {
        {
            const int e = tid >> 3, d4 = (tid & 7) * 4;
            const float4 v = *(const float4*)(C + (size_t)(e0 + e) * D_MODEL + d0 + d4);
            Cs[d4 + 0][e] = v.x; Cs[d4 + 1][e] = v.y;
            Cs[d4 + 2][e] = v.z; Cs[d4 + 3][e] = v.w;
        }
        #pragma unroll
        for (int r = 0; r < 2; ++r) {
            const int idx = tid + r * 256;
            const int d = idx >> 4, k4 = (idx & 15) * 4;
            *(float4*)&Ws[d][k4] =
                *(const float4*)(W + (size_t)(d0 + d) * D_MODEL + k0 + k4);
        }
        __syncthreads();
        #pragma unroll
        for (int dd = 0; dd < 32; ++dd) {
            const float2 a2 = *(const float2*)&Cs[dd][ty * 2];
            const double a0 = (double)a2.x, a1 = (double)a2.y;
            const float4 b4 = *(const float4*)&Ws[dd][tx * 4];
            const double b[4] = {(double)b4.x, (double)b4.y, (double)b4.z, (double)b4.w};
            #pragma unroll
            for (int j = 0; j < 4; ++j) { acc[0][j] += a0 * b[j]; acc[1][j] += a1 * b[j]; }
        }
        __syncthreads();
    }
    #pragma unroll
    for (int i = 0; i < 2; ++i) {
        const int e = e0 + ty * 2 + i;
        #pragma unroll
        for (int j = 0; j < 4; ++j)
            Mp[(size_t)e * D_MODEL + k0 + tx * 4 + j] = acc[i][j];
    }
}

// ---------------------------------------------------------------------------
// Kernel A2: combine 4 D-quarters -> M64, emit bf16 split Mh/Ml. grid 512x256.
// ---------------------------------------------------------------------------
__global__ __launch_bounds__(256) void cw_combine(
    const double* __restrict__ Mpart, double* __restrict__ M64,
    unsigned short* __restrict__ Mh, unsigned short* __restrict__ Ml)
{
    const int i4 = ((int)blockIdx.x * 256 + (int)threadIdx.x) * 4;
    const double* p0 = Mpart;
    const double* p1 = Mpart + (size_t)NUM_EXPERTS * D_MODEL;
    const double* p2 = Mpart + (size_t)2 * NUM_EXPERTS * D_MODEL;
    const double* p3 = Mpart + (size_t)3 * NUM_EXPERTS * D_MODEL;
    unsigned short hi[4], lo[4];
    #pragma unroll
    for (int u = 0; u < 4; ++u) {
        const double v = (p0[i4 + u] + p1[i4 + u]) + (p2[i4 + u] + p3[i4 + u]);
        M64[i4 + u] = v;
        const float f = (float)v;
        hi[u] = bf16_rne(f);
        lo[u] = bf16_rne(f - bf16_f32(hi[u]));
    }
    uint2 wh, wl;
    wh.x = (unsigned)hi[0] | ((unsigned)hi[1] << 16);
    wh.y = (unsigned)hi[2] | ((unsigned)hi[3] << 16);
    wl.x = (unsigned)lo[0] | ((unsigned)lo[1] << 16);
    wl.y = (unsigned)lo[2] | ((unsigned)lo[3] << 16);
    *(uint2*)(Mh + i4) = wh;
    *(uint2*)(Ml + i4) = wl;
}

// ---------------------------------------------------------------------------
// Kernel B: affinities via bf16-split MFMA (hh+hl+lh, f32 acc).
// tile 64t x 128e, BK=32, grid (256,2) = 512 blocks, 48KB LDS -> 3 blocks/CU.
// Counted-in-flight pipeline: raw s_barrier per chunk, NO vmcnt drain in the
// main loop. M staging is WAVE-PRIVATE (wave w glds-stages exactly the expert
// tiles its own MFMAs consume) -> no barrier needed for M; per-wave vmem
// ordering guarantees (GM(k) issued before LH(k+1); the compiler's register
// wait for stageH(k+1)'s H regs therefore retires GM(k) while leaving GM(k+1)
// in flight). H (shared across waves) is the only thing the barrier orders,
// and its ds_writes are covered by lgkmcnt(0) before each s_barrier.
// ---------------------------------------------------------------------------
__global__ __launch_bounds__(256, 3) void affinity_mfma(
    const float* __restrict__ H, const unsigned short* __restrict__ Mh,
    const unsigned short* __restrict__ Ml,
    float* __restrict__ aff, float* __restrict__ colsumPart)
{
    // fragment-order tiles: H 4 tiles x 64 lanes x 8 shorts; M 8 tiles.
    __shared__ unsigned short sHh[2][2048], sHl[2][2048];
    __shared__ unsigned short sMh[2][4096], sMl[2][4096];

    const int tid = threadIdx.x;
    const int lane = tid & 63, wv = tid >> 6;
    const int m = lane & 15, quad = lane >> 4;
    const int t0 = (int)blockIdx.x * 64;
    const int e0 = (int)blockIdx.y * 128;

    const int grp = tid >> 6;        // wave id 0..3
    const int q   = (tid >> 4) & 3;  // k-octet
    const int m16 = tid & 15;

    f32x4 acc[4][2];
    #pragma unroll
    for (int i = 0; i < 4; ++i)
        #pragma unroll
        for (int j = 0; j < 2; ++j) acc[i][j] = (f32x4){0.f, 0.f, 0.f, 0.f};

    float4 RAa, RAb, RBa, RBb;   // H prefetch regs (even / odd chunks)

    auto loadH = [&](int kc, float4& A, float4& B) {
        const int kb = kc * 32 + q * 8;
        const float* hp = H + (size_t)(t0 + grp * 16 + m16) * D_MODEL + kb;
        A = *(const float4*)hp;
        B = *(const float4*)(hp + 4);
    };
    auto stageH = [&](int b, const float4& A, const float4& B) {
        float x[8] = {A.x, A.y, A.z, A.w, B.x, B.y, B.z, B.w};
        unsigned short hi[8], lo[8];
        #pragma unroll
        for (int u = 0; u < 8; ++u) {
            hi[u] = bf16_rne(x[u]);
            lo[u] = bf16_rne(x[u] - bf16_f32(hi[u]));
        }
        uint4 ph, pl;
        ph.x = (unsigned)hi[0] | ((unsigned)hi[1] << 16);
        ph.y = (unsigned)hi[2] | ((unsigned)hi[3] << 16);
        ph.z = (unsigned)hi[4] | ((unsigned)hi[5] << 16);
        ph.w = (unsigned)hi[6] | ((unsigned)hi[7] << 16);
        pl.x = (unsigned)lo[0] | ((unsigned)lo[1] << 16);
        pl.y = (unsigned)lo[2] | ((unsigned)lo[3] << 16);
        pl.z = (unsigned)lo[4] | ((unsigned)lo[5] << 16);
        pl.w = (unsigned)lo[6] | ((unsigned)lo[7] << 16);
        *(uint4*)&sHh[b][grp * 512 + lane * 8] = ph;
        *(uint4*)&sHl[b][grp * 512 + lane * 8] = pl;
    };
    auto gldsM = [&](int kc, int b) {
        const int kb = kc * 32 + q * 8;
        #pragma unroll
        for (int s = 0; s < 2; ++s) {
            const int e = e0 + (grp * 2 + s) * 16 + m16;
            const size_t g = (size_t)e * D_MODEL + kb;
            glds16(Mh + g, &sMh[b][(grp * 2 + s) * 512]);
            glds16(Ml + g, &sMl[b][(grp * 2 + s) * 512]);
        }
    };
    auto mfmaT = [&](int b) {
        short8 ah[4], al[4], bh[2], bl[2];
        #pragma unroll
        for (int i = 0; i < 4; ++i) {
            ah[i] = *(const short8*)&sHh[b][i * 512 + lane * 8];
            al[i] = *(const short8*)&sHl[b][i * 512 + lane * 8];
        }
        #pragma unroll
        for (int j = 0; j < 2; ++j) {
            bh[j] = *(const short8*)&sMh[b][(wv * 2 + j) * 512 + lane * 8];
            bl[j] = *(const short8*)&sMl[b][(wv * 2 + j) * 512 + lane * 8];
        }
        #pragma unroll
        for (int i = 0; i < 4; ++i)
            #pragma unroll
            for (int j = 0; j < 2; ++j) {
                acc[i][j] = __builtin_amdgcn_mfma_f32_16x16x32_bf16(ah[i], bh[j], acc[i][j], 0, 0, 0);
                acc[i][j] = __builtin_amdgcn_mfma_f32_16x16x32_bf16(ah[i], bl[j], acc[i][j], 0, 0, 0);
                acc[i][j] = __builtin_amdgcn_mfma_f32_16x16x32_bf16(al[i], bh[j], acc[i][j], 0, 0, 0);
            }
    };

    // prologue: vmem issue order GM(0),GM(1),LH(0),LH(1); stageH(0)'s reg
    // wait retires GM(0),GM(1) (older than LH(0)).
    gldsM(0, 0);
    gldsM(1, 1);
    loadH(0, RAa, RAb);
    loadH(1, RBa, RBb);
    stageH(0, RAa, RAb);
    asm volatile("s_waitcnt lgkmcnt(0)" ::: "memory");
    __builtin_amdgcn_s_barrier();                   // B(-1): chunk0 ready

    for (int k = 0; k < 64; k += 2) {
        // ---- even body: compute chunk k from buf0 ----
        stageH(1, RBa, RBb);                        // SH(k+1); retires GM(k)
        if (k + 2 < 64) loadH(k + 2, RAa, RAb);     // LH(k+2)
        mfmaT(0);                                   // CP(k)
        if (k + 2 < 64) gldsM(k + 2, 0);            // GM(k+2) -> my buf0 M region
        asm volatile("s_waitcnt lgkmcnt(0)" ::: "memory");
        __builtin_amdgcn_s_barrier();               // B(k): chunk k+1 H ready

        // ---- odd body: compute chunk k+1 from buf1 ----
        if (k + 2 < 64) {
            stageH(0, RAa, RAb);                    // SH(k+2); retires GM(k+1)
        } else {
            asm volatile("s_waitcnt vmcnt(0)" ::: "memory");  // tail: drain GM(63)
        }
        if (k + 3 < 64) loadH(k + 3, RBa, RBb);     // LH(k+3)
        mfmaT(1);                                   // CP(k+1)
        if (k + 3 < 64) gldsM(k + 3, 1);            // GM(k+3) -> my buf1 M region
        asm volatile("s_waitcnt lgkmcnt(0)" ::: "memory");
        __builtin_amdgcn_s_barrier();               // B(k+1): chunk k+2 H ready
    }

    // epilogue: aff stores + sigmoid column partial sums (no atomics)
    #pragma unroll
    for (int j = 0; j < 2; ++j) {
        const int el = wv * 32 + j * 16 + m;   // local expert in [0,128)
        const int e = e0 + el;
        float colsum = 0.f;
        #pragma unroll
        for (int i = 0; i < 4; ++i) {
            const int tbase = t0 + i * 16 + quad * 4;
            #pragma unroll
            for (int r = 0; r < 4; ++r) {
                const float v = acc[i][j][r];
                aff[(size_t)(tbase + r) * NUM_EXPERTS + e] = v;
                colsum += 1.f / (1.f + expf(-v));
            }
        }
        colsum += __shfl_xor(colsum, 16, 64);
        colsum += __shfl_xor(colsum, 32, 64);
        if (quad == 0)
            colsumPart[((size_t)blockIdx.y * 256 + blockIdx.x) * 128 + el] = colsum;
    }
}

// ---------------------------------------------------------------------------
// Kernel C: fast top-9 (f32) on packed u64 keys + margin test.
// ---------------------------------------------------------------------------
__global__ __launch_bounds__(256) void topk_margin(
    const float* __restrict__ aff, const float* __restrict__ bias,
    float* __restrict__ out_idx, float* __restrict__ out_w,
    int* __restrict__ nmarg, int* __restrict__ list,
    int* __restrict__ ncand, int* __restrict__ cand)
{
    const int lane = threadIdx.x & 63;
    const int wv = threadIdx.x >> 6;
    const int t = blockIdx.x * 4 + wv;

    const float4 av = *(const float4*)(aff + (size_t)t * NUM_EXPERTS + lane * 4);
    const float4 bv = *(const float4*)(bias + lane * 4);
    float g[4], s0[4];
    g[0] = 1.f / (1.f + expf(-av.x)); s0[0] = g[0] + bv.x;
    g[1] = 1.f / (1.f + expf(-av.y)); s0[1] = g[1] + bv.y;
    g[2] = 1.f / (1.f + expf(-av.z)); s0[2] = g[2] + bv.z;
    g[3] = 1.f / (1.f + expf(-av.w)); s0[3] = g[3] + bv.w;

    unsigned long long kw[4];
    #pragma unroll
    for (int j = 0; j < 4; ++j)
        kw[j] = ((unsigned long long)ford(s0[j]) << 32)
              | (unsigned long long)(0xFFFFFFFFu - (unsigned)(lane * 4 + j));

    float wsum = 0.f, my_g = 0.f, prevs = 0.f, minGap = 1e30f, s8 = 0.f;
    int my_i = 0;

    #pragma unroll
    for (int it = 0; it < 9; ++it) {
        unsigned long long bk = kw[0];
        if (kw[1] > bk) bk = kw[1];
        if (kw[2] > bk) bk = kw[2];
        if (kw[3] > bk) bk = kw[3];
        #pragma unroll
        for (int off = 1; off < 64; off <<= 1) {
            const unsigned long long ok = __shfl_xor(bk, off, 64);
            if (ok > bk) bk = ok;
        }
        const unsigned o = (unsigned)(bk >> 32);
        const float sv = finv(o);
        const int e = (int)(0xFFFFFFFFu - (unsigned)(bk & 0xFFFFFFFFu));
        const int ej = e & 3, el = e >> 2;
        const float gl = (ej == 0) ? g[0] : (ej == 1) ? g[1] : (ej == 2) ? g[2] : g[3];
        const float gv = __shfl(gl, el, 64);
        if (it < TOP_K) {
            wsum += gv;
            if (lane == it) { my_i = e; my_g = gv; }
            if (it == 7) s8 = sv;
        }
        if (it > 0) minGap = fminf(minGap, prevs - sv);
        prevs = sv;
        if (lane == el) {
            if (ej == 0) kw[0] = 0ull; else if (ej == 1) kw[1] = 0ull;
            else if (ej == 2) kw[2] = 0ull; else kw[3] = 0ull;
        }
    }

    if (minGap < MARGIN) {
        int pos = 0;
        if (lane == 0) pos = atomicAdd(nmarg, 1);
        pos = __shfl(pos, 0, 64);
        const float thresh = s8 - MARGIN;
        int base = 0;
        #pragma unroll
        for (int j = 0; j < 4; ++j) {
            const bool c = (s0[j] >= thresh);
            const unsigned long long mk = __ballot(c);
            const int mypos = base + __popcll(mk & ((1ull << lane) - 1ull));
            if (c && mypos < 64) cand[(size_t)pos * 64 + mypos] = lane * 4 + j;
            base += (int)__popcll(mk);
        }
        if (lane == 0) { list[pos] = t; ncand[pos] = min(base, 64); }
    } else {
        const float inv = 1.f / (wsum + 1e-10f);
        if (lane < TOP_K) {
            out_idx[(size_t)t * TOP_K + lane] = (float)my_i;
            out_w[(size_t)t * TOP_K + lane] = my_g * inv;
        }
    }
}

// ---------------------------------------------------------------------------
// Kernel R: candidate-set f64 recheck.
// ---------------------------------------------------------------------------
__global__ __launch_bounds__(256) void recheck2(
    const float* __restrict__ H, const double* __restrict__ M64,
    const float* __restrict__ bias, const int* __restrict__ list,
    const int* __restrict__ ncand, const int* __restrict__ cand,
    const int* __restrict__ nmarg, float* __restrict__ out_idx,
    float* __restrict__ out_w)
{
    __shared__ float hsf[D_MODEL];
    __shared__ double sg[64], ssc[64];

    const int n = *nmarg;
    const int lane = threadIdx.x & 63, wv = threadIdx.x >> 6;

    for (int i = (int)blockIdx.x; i < n; i += (int)gridDim.x) {
        const int t = list[i];
        const int nc = ncand[i];

        for (int qd = threadIdx.x; qd < D_MODEL / 4; qd += 256)
            *(float4*)&hsf[qd * 4] = *(const float4*)(H + (size_t)t * D_MODEL + qd * 4);
        __syncthreads();

        for (int c = wv; c < nc; c += 4) {
            const int e = cand[(size_t)i * 64 + c];
            const double* mrow = M64 + (size_t)e * D_MODEL;
            double acc = 0.0;
            #pragma unroll 8
            for (int j = 0; j < 32; ++j) {
                const int k = lane + 64 * j;
                acc = fma((double)hsf[k], mrow[k], acc);
            }
            #pragma unroll
            for (int off = 1; off < 64; off <<= 1) acc += __shfl_xor(acc, off, 64);
            if (lane == 0) {
                const double gg = 1.0 / (1.0 + exp(-acc));
                sg[c] = gg;
                ssc[c] = gg + (double)bias[e];
            }
        }
        __syncthreads();

        if (wv == 0) {
            double s = -1e300, g = 0.0;
            int id = 1 << 20;
            if (lane < nc) { s = ssc[lane]; g = sg[lane]; id = cand[(size_t)i * 64 + lane]; }

            double wsum = 0.0, my_g = 0.0;
            int my_i = 0;
            for (int it = 0; it < TOP_K; ++it) {
                double bs = s, bg = g; int bi = id;
                #pragma unroll
                for (int off = 1; off < 64; off <<= 1) {
                    const double os = __shfl_xor(bs, off, 64);
                    const double og = __shfl_xor(bg, off, 64);
                    const int    oi = __shfl_xor(bi, off, 64);
                    if (os > bs || (os == bs && oi < bi)) { bs = os; bg = og; bi = oi; }
                }
                wsum += bg;
                if (lane == it) { my_i = bi; my_g = bg; }
                if (id == bi) s = -1e300;
            }
            const double inv = 1.0 / (wsum + 1e-10);
            if (lane < TOP_K) {
                out_idx[(size_t)t * TOP_K + lane] = (float)my_i;
                out_w[(size_t)t * TOP_K + lane] = (float)(my_g * inv);
            }
        }
        __syncthreads();
    }
}

// ---------------------------------------------------------------------------
// Kernel H: histogram out_idx -> counts; reduce colsumPart -> sumP.
// grid 64 x 256. colsumPart is [2][256][128].
// ---------------------------------------------------------------------------
__global__ __launch_bounds__(256) void hist_reduce(
    const float* __restrict__ out_idx, const float* __restrict__ colsumPart,
    int* __restrict__ counts, double* __restrict__ sumP)
{
    __shared__ int h[NUM_EXPERTS];
    const int tid = threadIdx.x;
    const int lane = tid & 63, wv = tid >> 6;
    h[tid] = 0;
    __syncthreads();
    for (int i = (int)blockIdx.x * 256 + tid; i < T_TOKENS * TOP_K; i += 64 * 256)
        atomicAdd(&h[(int)out_idx[i]], 1);
    __syncthreads();
    if (h[tid] != 0) atomicAdd(&counts[tid], h[tid]);

    const int e = (int)blockIdx.x * 4 + wv;
    const int half = e >> 7, el = e & 127;
    float ps = 0.f;
    for (int p = lane; p < 256; p += 64)
        ps += colsumPart[((size_t)half * 256 + p) * 128 + el];
    #pragma unroll
    for (int off = 1; off < 64; off <<= 1) ps += __shfl_xor(ps, off, 64);
    if (lane == 0) sumP[e] = (double)ps;
}

// ---------------------------------------------------------------------------
// Kernel D: balance loss
// ---------------------------------------------------------------------------
__global__ __launch_bounds__(256) void loss_f64(
    const double* __restrict__ sumP, const int* __restrict__ counts,
    float* __restrict__ out_loss)
{
    __shared__ double red[256];
    const int e = threadIdx.x;
    red[e] = (double)counts[e] * sumP[e];
    __syncthreads();
    #pragma unroll
    for (int sft = 128; sft > 0; sft >>= 1) {
        if (e < sft) red[e] += red[e + sft];
        __syncthreads();
    }
    if (e == 0) {
        const double denom = (double)T_TOKENS * (double)TOP_K * (double)T_TOKENS;
        out_loss[0] = (float)(0.001 * ((double)NUM_EXPERTS / (double)TOP_K) * red[0] / denom);
    }
}

extern "C" void kernel_launch(void* const* d_in, const int* in_sizes, int n_in,
                              void* d_out, int out_size, void* d_ws, size_t ws_size,
                              hipStream_t stream) {
    (void)in_sizes; (void)n_in; (void)out_size; (void)ws_size;
    const float* hidden = (const float*)d_in[0];
    const float* W      = (const float*)d_in[1];
    const float* C      = (const float*)d_in[2];
    const float* bias   = (const float*)d_in[3];
    float* out = (float*)d_out;
    char* ws   = (char*)d_ws;

    double*         M64    = (double*)(ws + WS_M64_B);
    unsigned short* Mh     = (unsigned short*)(ws + WS_MH_B);
    unsigned short* Ml     = (unsigned short*)(ws + WS_ML_B);
    double*         sumP   = (double*)(ws + WS_SUMP_B);
    int*            counts = (int*)(ws + WS_CNT_B);
    int*            nmarg  = (int*)(ws + WS_NMARG_B);
    int*            list   = (int*)(ws + WS_LIST_B);
    int*            ncand  = (int*)(ws + WS_NCAND_B);
    int*            cand   = (int*)(ws + WS_CAND_B);
    float*          csp    = (float*)(ws + WS_CSP_B);
    double*         Mpart  = (double*)(ws + WS_MP_B);

    hipMemsetAsync(ws + WS_CNT_B, 0, NUM_EXPERTS * 4 + 16, stream);

    cw_gemm_part<<<dim3(D_MODEL / 64, NUM_EXPERTS / 32, 4), 256, 0, stream>>>(C, W, Mpart);
    cw_combine<<<dim3(NUM_EXPERTS * D_MODEL / 1024), 256, 0, stream>>>(Mpart, M64, Mh, Ml);

    affinity_mfma<<<dim3(T_TOKENS / 64, 2), 256, 0, stream>>>(hidden, Mh, Ml, out + OUT_AFF, csp);

    topk_margin<<<dim3(T_TOKENS / 4), 256, 0, stream>>>(
        out + OUT_AFF, bias, out + OUT_IDX, out + OUT_W, nmarg, list, ncand, cand);

    recheck2<<<dim3(2048), 256, 0, stream>>>(
        hidden, M64, bias, list, ncand, cand, nmarg, out + OUT_IDX, out + OUT_W);

    hist_reduce<<<dim3(64), 256, 0, stream>>>(out + OUT_IDX, csp, counts, sumP);

    loss_f64<<<dim3(1), 256, 0, stream>>>(sumP, counts, out + OUT_LOSS);
}

// Round 4
// 386.364 us; speedup vs baseline: 1.1754x; 1.0174x over previous
//
#include <hip/hip_runtime.h>
#include <math.h>

#define T_TOKENS    16384
#define D_MODEL     2048
#define NUM_EXPERTS 256
#define TOP_K       8
#define MARGIN      6e-5f

// d_out layout (floats): idx | weights | affinities | loss
#define OUT_IDX  0
#define OUT_W    (T_TOKENS * TOP_K)
#define OUT_AFF  (2 * T_TOKENS * TOP_K)
#define OUT_LOSS (2 * T_TOKENS * TOP_K + T_TOKENS * NUM_EXPERTS)

// ws layout (bytes)
#define WS_M64_B   ((size_t)0)                                    // double[256*2048] 4MB
#define WS_MH_B    (WS_M64_B + (size_t)NUM_EXPERTS * D_MODEL * 8) // bf16 1MB
#define WS_ML_B    (WS_MH_B  + (size_t)NUM_EXPERTS * D_MODEL * 2) // bf16 1MB
#define WS_SUMP_B  (WS_ML_B  + (size_t)NUM_EXPERTS * D_MODEL * 2) // double[256]
#define WS_CNT_B   (WS_SUMP_B + NUM_EXPERTS * 8)                  // int[256]
#define WS_NMARG_B (WS_CNT_B  + NUM_EXPERTS * 4)                  // int nmarg, int done (+pad)
#define WS_LIST_B  (WS_NMARG_B + 16)                              // int[16384]
#define WS_NCAND_B (WS_LIST_B + (size_t)T_TOKENS * 4)             // int[16384]
#define WS_CAND_B  (WS_NCAND_B + (size_t)T_TOKENS * 4)            // int[16384*64] 4MB
#define WS_CSP_B   (WS_CAND_B + (size_t)T_TOKENS * 64 * 4)        // float[2*256*128] 256KB (slot 4MB)
#define WS_MP_B    (WS_CSP_B + (size_t)4096 * 256 * 4)            // double[4][256*2048] 16MB

typedef __attribute__((ext_vector_type(8))) short short8;
typedef __attribute__((ext_vector_type(4))) float f32x4;

__device__ __forceinline__ unsigned short bf16_rne(float x) {
    unsigned u = __float_as_uint(x);
    u += 0x7FFFu + ((u >> 16) & 1u);
    return (unsigned short)(u >> 16);
}
__device__ __forceinline__ float bf16_f32(unsigned short h) {
    return __uint_as_float(((unsigned)h) << 16);
}
__device__ __forceinline__ unsigned ford(float f) {
    unsigned u = __float_as_uint(f);
    return ((int)u >= 0) ? (u | 0x80000000u) : ~u;
}
__device__ __forceinline__ float finv(unsigned o) {
    return (o & 0x80000000u) ? __uint_as_float(o ^ 0x80000000u)
                             : __uint_as_float(~o);
}
// async global->LDS, 16B per lane; LDS dest = wave-uniform base + lane*16
__device__ __forceinline__ void glds16(const void* g, void* l) {
    __builtin_amdgcn_global_load_lds(
        (const __attribute__((address_space(1))) unsigned int*)g,
        (__attribute__((address_space(3))) unsigned int*)l,
        16, 0, 0);
}

// ---------------------------------------------------------------------------
// Kernel A1: partial M = C @ W over a D-quarter. tile 32e x 64k, grid (32,8,4)
// = 1024 blocks (4 blocks/CU for latency hiding).
// ---------------------------------------------------------------------------
__global__ __launch_bounds__(256, 4) void cw_gemm_part(
    const float* __restrict__ C, const float* __restrict__ W,
    double* __restrict__ Mpart)
{
    __shared__ float Cs[32][34];
    __shared__ float Ws[32][68];

    const int tid = threadIdx.x;
    const int tx = tid & 15;
    const int ty = tid >> 4;
    const int e0 = blockIdx.y * 32;
    const int k0 = blockIdx.x * 64;
    const int z  = blockIdx.z;

    double* Mp = Mpart + (size_t)z * NUM_EXPERTS * D_MODEL;
    double acc[2][4] = {{0,0,0,0},{0,0,0,0}};

    for (int d0 = z * 512; d0 < (z + 1) * 512; d0 += 32) {
        {
            const int e = tid >> 3, d4 = (tid & 7) * 4;
            const float4 v = *(const float4*)(C + (size_t)(e0 + e) * D_MODEL + d0 + d4);
            Cs[d4 + 0][e] = v.x; Cs[d4 + 1][e] = v.y;
            Cs[d4 + 2][e] = v.z; Cs[d4 + 3][e] = v.w;
        }
        #pragma unroll
        for (int r = 0; r < 2; ++r) {
            const int idx = tid + r * 256;
            const int d = idx >> 4, k4 = (idx & 15) * 4;
            *(float4*)&Ws[d][k4] =
                *(const float4*)(W + (size_t)(d0 + d) * D_MODEL + k0 + k4);
        }
        __syncthreads();
        #pragma unroll
        for (int dd = 0; dd < 32; ++dd) {
            const float2 a2 = *(const float2*)&Cs[dd][ty * 2];
            const double a0 = (double)a2.x, a1 = (double)a2.y;
            const float4 b4 = *(const float4*)&Ws[dd][tx * 4];
            const double b[4] = {(double)b4.x, (double)b4.y, (double)b4.z, (double)b4.w};
            #pragma unroll
            for (int j = 0; j < 4; ++j) { acc[0][j] += a0 * b[j]; acc[1][j] += a1 * b[j]; }
        }
        __syncthreads();
    }
    #pragma unroll
    for (int i = 0; i < 2; ++i) {
        const int e = e0 + ty * 2 + i;
        #pragma unroll
        for (int j = 0; j < 4; ++j)
            Mp[(size_t)e * D_MODEL + k0 + tx * 4 + j] = acc[i][j];
    }
}

// ---------------------------------------------------------------------------
// Kernel A2: combine 4 D-quarters -> M64, emit bf16 split Mh/Ml. grid 512x256.
// ---------------------------------------------------------------------------
__global__ __launch_bounds__(256) void cw_combine(
    const double* __restrict__ Mpart, double* __restrict__ M64,
    unsigned short* __restrict__ Mh, unsigned short* __restrict__ Ml)
{
    const int i4 = ((int)blockIdx.x * 256 + (int)threadIdx.x) * 4;
    const double* p0 = Mpart;
    const double* p1 = Mpart + (size_t)NUM_EXPERTS * D_MODEL;
    const double* p2 = Mpart + (size_t)2 * NUM_EXPERTS * D_MODEL;
    const double* p3 = Mpart + (size_t)3 * NUM_EXPERTS * D_MODEL;
    unsigned short hi[4], lo[4];
    #pragma unroll
    for (int u = 0; u < 4; ++u) {
        const double v = (p0[i4 + u] + p1[i4 + u]) + (p2[i4 + u] + p3[i4 + u]);
        M64[i4 + u] = v;
        const float f = (float)v;
        hi[u] = bf16_rne(f);
        lo[u] = bf16_rne(f - bf16_f32(hi[u]));
    }
    uint2 wh, wl;
    wh.x = (unsigned)hi[0] | ((unsigned)hi[1] << 16);
    wh.y = (unsigned)hi[2] | ((unsigned)hi[3] << 16);
    wl.x = (unsigned)lo[0] | ((unsigned)lo[1] << 16);
    wl.y = (unsigned)lo[2] | ((unsigned)lo[3] << 16);
    *(uint2*)(Mh + i4) = wh;
    *(uint2*)(Ml + i4) = wl;
}

// ---------------------------------------------------------------------------
// Kernel B: affinities via bf16-split MFMA (hh+hl+lh, f32 acc).
// tile 64t x 128e, BK=64 (32 chunks, 48 MFMA/wave per barrier-pair), grid
// (256,2) = 512 blocks, 64KB LDS -> 2 blocks/CU.
// Counted-in-flight pipeline (R3-verified): raw s_barrier + lgkmcnt(0) only;
// no vmcnt drain in the main loop. M-hi staged via wave-private
// global_load_lds; M-lo loaded straight to REGISTERS (per-lane uint4 from
// L2-resident Ml, prefetch distance 2) - removes 16KB/buf LDS and 4 ds_reads.
// Issue-order invariant: GM(k) older than LH(k+1), so stageH(k+1)'s register
// wait retires the glds feeding chunk k before its ds_reads.
// ---------------------------------------------------------------------------
struct HRegs  { float4 a[2][2]; };   // [kk][half]: 8 floats per kk
struct MlRegs { uint4  r[2][2]; };   // [j][kk]

__global__ __launch_bounds__(256, 2) void affinity_mfma(
    const float* __restrict__ H, const unsigned short* __restrict__ Mh,
    const unsigned short* __restrict__ Ml,
    float* __restrict__ aff, float* __restrict__ colsumPart)
{
    // fragment-order tiles: per buf: H 2kk x 4 t-tiles x (64 lanes x 8 sh);
    // Mh 2kk x 8 e-tiles x (64 lanes x 8 sh).
    __shared__ unsigned short sHh[2][4096], sHl[2][4096];
    __shared__ unsigned short sMh[2][8192];

    const int tid = threadIdx.x;
    const int lane = tid & 63, wv = tid >> 6;
    const int m = lane & 15, quad = lane >> 4;
    const int t0 = (int)blockIdx.x * 64;
    const int e0 = (int)blockIdx.y * 128;

    const int grp = tid >> 6;        // wave id 0..3
    const int q   = (tid >> 4) & 3;  // k-octet within 32
    const int m16 = tid & 15;

    f32x4 acc[4][2];
    #pragma unroll
    for (int i = 0; i < 4; ++i)
        #pragma unroll
        for (int j = 0; j < 2; ++j) acc[i][j] = (f32x4){0.f, 0.f, 0.f, 0.f};

    HRegs RA, RB;       // H prefetch regs (even / odd chunks)
    MlRegs RLA, RLB;    // Ml prefetch regs (even / odd chunks)

    auto loadH = [&](int kc, HRegs& R) {
        const float* hp = H + (size_t)(t0 + grp * 16 + m16) * D_MODEL + kc * 64 + q * 8;
        #pragma unroll
        for (int kk = 0; kk < 2; ++kk) {
            R.a[kk][0] = *(const float4*)(hp + kk * 32);
            R.a[kk][1] = *(const float4*)(hp + kk * 32 + 4);
        }
    };
    auto loadMl = [&](int kc, MlRegs& R) {
        #pragma unroll
        for (int j = 0; j < 2; ++j) {
            const unsigned short* mp =
                Ml + (size_t)(e0 + (wv * 2 + j) * 16 + m) * D_MODEL + kc * 64 + quad * 8;
            #pragma unroll
            for (int kk = 0; kk < 2; ++kk)
                R.r[j][kk] = *(const uint4*)(mp + kk * 32);
        }
    };
    auto stageH = [&](int b, const HRegs& R) {
        #pragma unroll
        for (int kk = 0; kk < 2; ++kk) {
            const float4 A = R.a[kk][0], B = R.a[kk][1];
            float x[8] = {A.x, A.y, A.z, A.w, B.x, B.y, B.z, B.w};
            unsigned short hi[8], lo[8];
            #pragma unroll
            for (int u = 0; u < 8; ++u) {
                hi[u] = bf16_rne(x[u]);
                lo[u] = bf16_rne(x[u] - bf16_f32(hi[u]));
            }
            uint4 ph, pl;
            ph.x = (unsigned)hi[0] | ((unsigned)hi[1] << 16);
            ph.y = (unsigned)hi[2] | ((unsigned)hi[3] << 16);
            ph.z = (unsigned)hi[4] | ((unsigned)hi[5] << 16);
            ph.w = (unsigned)hi[6] | ((unsigned)hi[7] << 16);
            pl.x = (unsigned)lo[0] | ((unsigned)lo[1] << 16);
            pl.y = (unsigned)lo[2] | ((unsigned)lo[3] << 16);
            pl.z = (unsigned)lo[4] | ((unsigned)lo[5] << 16);
            pl.w = (unsigned)lo[6] | ((unsigned)lo[7] << 16);
            *(uint4*)&sHh[b][kk * 2048 + grp * 512 + lane * 8] = ph;
            *(uint4*)&sHl[b][kk * 2048 + grp * 512 + lane * 8] = pl;
        }
    };
    auto gldsM = [&](int kc, int b) {
        #pragma unroll
        for (int s = 0; s < 2; ++s) {
            const unsigned short* mp =
                Mh + (size_t)(e0 + (grp * 2 + s) * 16 + m16) * D_MODEL + kc * 64 + q * 8;
            #pragma unroll
            for (int kk = 0; kk < 2; ++kk)
                glds16(mp + kk * 32, &sMh[b][kk * 4096 + (grp * 2 + s) * 512]);
        }
    };
    auto mfmaT = [&](int b, const MlRegs& RL) {
        #pragma unroll
        for (int kk = 0; kk < 2; ++kk) {
            short8 ah[4], al[4], bh[2], bl[2];
            #pragma unroll
            for (int i = 0; i < 4; ++i) {
                ah[i] = *(const short8*)&sHh[b][kk * 2048 + i * 512 + lane * 8];
                al[i] = *(const short8*)&sHl[b][kk * 2048 + i * 512 + lane * 8];
            }
            #pragma unroll
            for (int j = 0; j < 2; ++j) {
                bh[j] = *(const short8*)&sMh[b][kk * 4096 + (wv * 2 + j) * 512 + lane * 8];
                bl[j] = *(const short8*)&RL.r[j][kk];
            }
            __builtin_amdgcn_s_setprio(1);
            #pragma unroll
            for (int i = 0; i < 4; ++i)
                #pragma unroll
                for (int j = 0; j < 2; ++j) {
                    acc[i][j] = __builtin_amdgcn_mfma_f32_16x16x32_bf16(ah[i], bh[j], acc[i][j], 0, 0, 0);
                    acc[i][j] = __builtin_amdgcn_mfma_f32_16x16x32_bf16(ah[i], bl[j], acc[i][j], 0, 0, 0);
                    acc[i][j] = __builtin_amdgcn_mfma_f32_16x16x32_bf16(al[i], bh[j], acc[i][j], 0, 0, 0);
                }
            __builtin_amdgcn_s_setprio(0);
        }
    };

    // prologue: vmem issue order GM(0),GM(1),LH(0),LH(1),RL(0),RL(1);
    // stageH(0)'s reg wait (LH(0)) retires GM(0),GM(1).
    gldsM(0, 0);
    gldsM(1, 1);
    loadH(0, RA);
    loadH(1, RB);
    loadMl(0, RLA);
    loadMl(1, RLB);
    stageH(0, RA);
    asm volatile("s_waitcnt lgkmcnt(0)" ::: "memory");
    __builtin_amdgcn_s_barrier();                   // chunk0 ready

    for (int k = 0; k < 32; k += 2) {
        // ---- even body: compute chunk k from buf0 ----
        stageH(1, RB);                              // SH(k+1); retires GM(k)
        if (k + 2 < 32) loadH(k + 2, RA);           // LH(k+2)
        mfmaT(0, RLA);                              // CP(k)
        if (k + 2 < 32) loadMl(k + 2, RLA);         // RL(k+2)
        if (k + 2 < 32) gldsM(k + 2, 0);            // GM(k+2) -> my buf0 M region
        asm volatile("s_waitcnt lgkmcnt(0)" ::: "memory");
        __builtin_amdgcn_s_barrier();               // chunk k+1 H ready

        // ---- odd body: compute chunk k+1 from buf1 ----
        if (k + 2 < 32) {
            stageH(0, RA);                          // SH(k+2); retires GM(k+1)
        } else {
            asm volatile("s_waitcnt vmcnt(0)" ::: "memory");  // tail drain
        }
        if (k + 3 < 32) loadH(k + 3, RB);           // LH(k+3)
        mfmaT(1, RLB);                              // CP(k+1)
        if (k + 3 < 32) loadMl(k + 3, RLB);         // RL(k+3)
        if (k + 3 < 32) gldsM(k + 3, 1);            // GM(k+3) -> my buf1 M region
        asm volatile("s_waitcnt lgkmcnt(0)" ::: "memory");
        __builtin_amdgcn_s_barrier();               // chunk k+2 H ready
    }

    // epilogue: aff stores + sigmoid column partial sums (no atomics)
    #pragma unroll
    for (int j = 0; j < 2; ++j) {
        const int el = wv * 32 + j * 16 + m;   // local expert in [0,128)
        const int e = e0 + el;
        float colsum = 0.f;
        #pragma unroll
        for (int i = 0; i < 4; ++i) {
            const int tbase = t0 + i * 16 + quad * 4;
            #pragma unroll
            for (int r = 0; r < 4; ++r) {
                const float v = acc[i][j][r];
                aff[(size_t)(tbase + r) * NUM_EXPERTS + e] = v;
                colsum += 1.f / (1.f + expf(-v));
            }
        }
        colsum += __shfl_xor(colsum, 16, 64);
        colsum += __shfl_xor(colsum, 32, 64);
        if (quad == 0)
            colsumPart[((size_t)blockIdx.y * 256 + blockIdx.x) * 128 + el] = colsum;
    }
}

// ---------------------------------------------------------------------------
// Kernel C: fast top-9 (f32) on packed u64 keys + margin test.
// ---------------------------------------------------------------------------
__global__ __launch_bounds__(256) void topk_margin(
    const float* __restrict__ aff, const float* __restrict__ bias,
    float* __restrict__ out_idx, float* __restrict__ out_w,
    int* __restrict__ nmarg, int* __restrict__ list,
    int* __restrict__ ncand, int* __restrict__ cand)
{
    const int lane = threadIdx.x & 63;
    const int wv = threadIdx.x >> 6;
    const int t = blockIdx.x * 4 + wv;

    const float4 av = *(const float4*)(aff + (size_t)t * NUM_EXPERTS + lane * 4);
    const float4 bv = *(const float4*)(bias + lane * 4);
    float g[4], s0[4];
    g[0] = 1.f / (1.f + expf(-av.x)); s0[0] = g[0] + bv.x;
    g[1] = 1.f / (1.f + expf(-av.y)); s0[1] = g[1] + bv.y;
    g[2] = 1.f / (1.f + expf(-av.z)); s0[2] = g[2] + bv.z;
    g[3] = 1.f / (1.f + expf(-av.w)); s0[3] = g[3] + bv.w;

    unsigned long long kw[4];
    #pragma unroll
    for (int j = 0; j < 4; ++j)
        kw[j] = ((unsigned long long)ford(s0[j]) << 32)
              | (unsigned long long)(0xFFFFFFFFu - (unsigned)(lane * 4 + j));

    float wsum = 0.f, my_g = 0.f, prevs = 0.f, minGap = 1e30f, s8 = 0.f;
    int my_i = 0;

    #pragma unroll
    for (int it = 0; it < 9; ++it) {
        unsigned long long bk = kw[0];
        if (kw[1] > bk) bk = kw[1];
        if (kw[2] > bk) bk = kw[2];
        if (kw[3] > bk) bk = kw[3];
        #pragma unroll
        for (int off = 1; off < 64; off <<= 1) {
            const unsigned long long ok = __shfl_xor(bk, off, 64);
            if (ok > bk) bk = ok;
        }
        const unsigned o = (unsigned)(bk >> 32);
        const float sv = finv(o);
        const int e = (int)(0xFFFFFFFFu - (unsigned)(bk & 0xFFFFFFFFu));
        const int ej = e & 3, el = e >> 2;
        const float gl = (ej == 0) ? g[0] : (ej == 1) ? g[1] : (ej == 2) ? g[2] : g[3];
        const float gv = __shfl(gl, el, 64);
        if (it < TOP_K) {
            wsum += gv;
            if (lane == it) { my_i = e; my_g = gv; }
            if (it == 7) s8 = sv;
        }
        if (it > 0) minGap = fminf(minGap, prevs - sv);
        prevs = sv;
        if (lane == el) {
            if (ej == 0) kw[0] = 0ull; else if (ej == 1) kw[1] = 0ull;
            else if (ej == 2) kw[2] = 0ull; else kw[3] = 0ull;
        }
    }

    if (minGap < MARGIN) {
        int pos = 0;
        if (lane == 0) pos = atomicAdd(nmarg, 1);
        pos = __shfl(pos, 0, 64);
        const float thresh = s8 - MARGIN;
        int base = 0;
        #pragma unroll
        for (int j = 0; j < 4; ++j) {
            const bool c = (s0[j] >= thresh);
            const unsigned long long mk = __ballot(c);
            const int mypos = base + __popcll(mk & ((1ull << lane) - 1ull));
            if (c && mypos < 64) cand[(size_t)pos * 64 + mypos] = lane * 4 + j;
            base += (int)__popcll(mk);
        }
        if (lane == 0) { list[pos] = t; ncand[pos] = min(base, 64); }
    } else {
        const float inv = 1.f / (wsum + 1e-10f);
        if (lane < TOP_K) {
            out_idx[(size_t)t * TOP_K + lane] = (float)my_i;
            out_w[(size_t)t * TOP_K + lane] = my_g * inv;
        }
    }
}

// ---------------------------------------------------------------------------
// Kernel R: candidate-set f64 recheck.
// ---------------------------------------------------------------------------
__global__ __launch_bounds__(256) void recheck2(
    const float* __restrict__ H, const double* __restrict__ M64,
    const float* __restrict__ bias, const int* __restrict__ list,
    const int* __restrict__ ncand, const int* __restrict__ cand,
    const int* __restrict__ nmarg, float* __restrict__ out_idx,
    float* __restrict__ out_w)
{
    __shared__ float hsf[D_MODEL];
    __shared__ double sg[64], ssc[64];

    const int n = *nmarg;
    const int lane = threadIdx.x & 63, wv = threadIdx.x >> 6;

    for (int i = (int)blockIdx.x; i < n; i += (int)gridDim.x) {
        const int t = list[i];
        const int nc = ncand[i];

        for (int qd = threadIdx.x; qd < D_MODEL / 4; qd += 256)
            *(float4*)&hsf[qd * 4] = *(const float4*)(H + (size_t)t * D_MODEL + qd * 4);
        __syncthreads();

        for (int c = wv; c < nc; c += 4) {
            const int e = cand[(size_t)i * 64 + c];
            const double* mrow = M64 + (size_t)e * D_MODEL;
            double acc = 0.0;
            #pragma unroll 8
            for (int j = 0; j < 32; ++j) {
                const int k = lane + 64 * j;
                acc = fma((double)hsf[k], mrow[k], acc);
            }
            #pragma unroll
            for (int off = 1; off < 64; off <<= 1) acc += __shfl_xor(acc, off, 64);
            if (lane == 0) {
                const double gg = 1.0 / (1.0 + exp(-acc));
                sg[c] = gg;
                ssc[c] = gg + (double)bias[e];
            }
        }
        __syncthreads();

        if (wv == 0) {
            double s = -1e300, g = 0.0;
            int id = 1 << 20;
            if (lane < nc) { s = ssc[lane]; g = sg[lane]; id = cand[(size_t)i * 64 + lane]; }

            double wsum = 0.0, my_g = 0.0;
            int my_i = 0;
            for (int it = 0; it < TOP_K; ++it) {
                double bs = s, bg = g; int bi = id;
                #pragma unroll
                for (int off = 1; off < 64; off <<= 1) {
                    const double os = __shfl_xor(bs, off, 64);
                    const double og = __shfl_xor(bg, off, 64);
                    const int    oi = __shfl_xor(bi, off, 64);
                    if (os > bs || (os == bs && oi < bi)) { bs = os; bg = og; bi = oi; }
                }
                wsum += bg;
                if (lane == it) { my_i = bi; my_g = bg; }
                if (id == bi) s = -1e300;
            }
            const double inv = 1.0 / (wsum + 1e-10);
            if (lane < TOP_K) {
                out_idx[(size_t)t * TOP_K + lane] = (float)my_i;
                out_w[(size_t)t * TOP_K + lane] = (float)(my_g * inv);
            }
        }
        __syncthreads();
    }
}

// ---------------------------------------------------------------------------
// Kernel H: histogram out_idx -> counts; reduce colsumPart -> sumP; the
// LAST block (ticket pattern) computes the balance loss. grid 64 x 256.
// Cross-XCD safety: counts/sumP read back via device-scope atomics.
// ---------------------------------------------------------------------------
__global__ __launch_bounds__(256) void hist_reduce_loss(
    const float* __restrict__ out_idx, const float* __restrict__ colsumPart,
    int* __restrict__ counts, double* __restrict__ sumP,
    int* __restrict__ done, float* __restrict__ out_loss)
{
    __shared__ int h[NUM_EXPERTS];
    __shared__ int ticket;
    const int tid = threadIdx.x;
    const int lane = tid & 63, wv = tid >> 6;
    h[tid] = 0;
    __syncthreads();
    for (int i = (int)blockIdx.x * 256 + tid; i < T_TOKENS * TOP_K; i += 64 * 256)
        atomicAdd(&h[(int)out_idx[i]], 1);
    __syncthreads();
    if (h[tid] != 0) atomicAdd(&counts[tid], h[tid]);

    const int e = (int)blockIdx.x * 4 + wv;
    const int half = e >> 7, el = e & 127;
    float ps = 0.f;
    for (int p = lane; p < 256; p += 64)
        ps += colsumPart[((size_t)half * 256 + p) * 128 + el];
    #pragma unroll
    for (int off = 1; off < 64; off <<= 1) ps += __shfl_xor(ps, off, 64);
    if (lane == 0) sumP[e] = (double)ps;

    // last-block loss
    __threadfence();
    __syncthreads();
    if (tid == 0) ticket = atomicAdd(done, 1);
    __syncthreads();
    if (ticket == 63) {
        __shared__ double red[256];
        const int c = atomicAdd(&counts[tid], 0);          // coherent read
        const double sp = atomicAdd(&sumP[tid], 0.0);      // coherent read
        red[tid] = (double)c * sp;
        __syncthreads();
        #pragma unroll
        for (int sft = 128; sft > 0; sft >>= 1) {
            if (tid < sft) red[tid] += red[tid + sft];
            __syncthreads();
        }
        if (tid == 0) {
            const double denom = (double)T_TOKENS * (double)TOP_K * (double)T_TOKENS;
            out_loss[0] = (float)(0.001 * ((double)NUM_EXPERTS / (double)TOP_K) * red[0] / denom);
        }
    }
}

extern "C" void kernel_launch(void* const* d_in, const int* in_sizes, int n_in,
                              void* d_out, int out_size, void* d_ws, size_t ws_size,
                              hipStream_t stream) {
    (void)in_sizes; (void)n_in; (void)out_size; (void)ws_size;
    const float* hidden = (const float*)d_in[0];
    const float* W      = (const float*)d_in[1];
    const float* C      = (const float*)d_in[2];
    const float* bias   = (const float*)d_in[3];
    float* out = (float*)d_out;
    char* ws   = (char*)d_ws;

    double*         M64    = (double*)(ws + WS_M64_B);
    unsigned short* Mh     = (unsigned short*)(ws + WS_MH_B);
    unsigned short* Ml     = (unsigned short*)(ws + WS_ML_B);
    double*         sumP   = (double*)(ws + WS_SUMP_B);
    int*            counts = (int*)(ws + WS_CNT_B);
    int*            nmarg  = (int*)(ws + WS_NMARG_B);
    int*            done   = (int*)(ws + WS_NMARG_B) + 1;
    int*            list   = (int*)(ws + WS_LIST_B);
    int*            ncand  = (int*)(ws + WS_NCAND_B);
    int*            cand   = (int*)(ws + WS_CAND_B);
    float*          csp    = (float*)(ws + WS_CSP_B);
    double*         Mpart  = (double*)(ws + WS_MP_B);

    hipMemsetAsync(ws + WS_CNT_B, 0, NUM_EXPERTS * 4 + 16, stream);

    cw_gemm_part<<<dim3(D_MODEL / 64, NUM_EXPERTS / 32, 4), 256, 0, stream>>>(C, W, Mpart);
    cw_combine<<<dim3(NUM_EXPERTS * D_MODEL / 1024), 256, 0, stream>>>(Mpart, M64, Mh, Ml);

    affinity_mfma<<<dim3(T_TOKENS / 64, 2), 256, 0, stream>>>(hidden, Mh, Ml, out + OUT_AFF, csp);

    topk_margin<<<dim3(T_TOKENS / 4), 256, 0, stream>>>(
        out + OUT_AFF, bias, out + OUT_IDX, out + OUT_W, nmarg, list, ncand, cand);

    recheck2<<<dim3(2048), 256, 0, stream>>>(
        hidden, M64, bias, list, ncand, cand, nmarg, out + OUT_IDX, out + OUT_W);

    hist_reduce_loss<<<dim3(64), 256, 0, stream>>>(
        out + OUT_IDX, csp, counts, sumP, done, out + OUT_LOSS);
}